// Round 2
// baseline (32794.803 us; speedup 1.0000x reference)
//
#include <hip/hip_runtime.h>
#include <hip/hip_bf16.h>
#include <math.h>

#define LL 6
#define HH 6
#define DD 64
#define EE 384
#define FF 1536
#define TT 256
#define BB 256
#define VV 65
constexpr int BT = BB * TT;                 // 65536 rows total

// ---------------- embed: x = tok_emb[inputs] + pos_emb (chunk rows) ----------------
// Called with inp pre-offset to the chunk; rows are chunk-local; r0 multiple of 256
// so t = local_row % 256 is correct.
__global__ __launch_bounds__(256)
void embed_kernel(const int* __restrict__ inp, const float* __restrict__ tok,
                  const float* __restrict__ pos, float* __restrict__ x) {
  int idx = blockIdx.x * 256 + threadIdx.x;      // over R*EE/4, exact grid
  int e4 = idx % (EE / 4);
  int r = idx / (EE / 4);
  int t = r % TT;
  int tk = inp[r];
  float4 a = ((const float4*)tok)[tk * (EE / 4) + e4];
  float4 p = ((const float4*)pos)[t * (EE / 4) + e4];
  float4 o;
  o.x = a.x + p.x; o.y = a.y + p.y; o.z = a.z + p.z; o.w = a.w + p.w;
  ((float4*)x)[idx] = o;
}

// ------------- reshape Wq/Wk/Wv: [l][h][e][d] -> [l][e][h*D+d] -------------
__global__ __launch_bounds__(256)
void transpose_qkv_kernel(const float* __restrict__ Wq, const float* __restrict__ Wk,
                          const float* __restrict__ Wv, float* __restrict__ qT,
                          float* __restrict__ kT, float* __restrict__ vT) {
  int idx = blockIdx.x * 256 + threadIdx.x;      // over LL*EE*EE, exact grid
  int l = idx / (EE * EE);
  int r = idx % (EE * EE);
  int e = r / EE;
  int c = r % EE;
  int h = c >> 6, d = c & 63;
  int src = ((l * HH + h) * EE + e) * DD + d;
  qT[idx] = Wq[src];
  kT[idx] = Wk[src];
  vT[idx] = Wv[src];
}

// ---------------- layernorm over E=384, one wave per row ----------------
__global__ __launch_bounds__(256)
void layernorm_384(const float* __restrict__ x, const float* __restrict__ g,
                   const float* __restrict__ b, float* __restrict__ out) {
  int wid = threadIdx.x >> 6, lane = threadIdx.x & 63;
  int row = blockIdx.x * 4 + wid;
  const float* xr = x + (size_t)row * EE;
  float v[6];
  float s = 0.f, s2 = 0.f;
#pragma unroll
  for (int i = 0; i < 6; ++i) {
    v[i] = xr[lane + 64 * i];
    s += v[i];
    s2 += v[i] * v[i];
  }
#pragma unroll
  for (int off = 32; off; off >>= 1) {
    s += __shfl_xor(s, off);
    s2 += __shfl_xor(s2, off);
  }
  float mu = s * (1.f / EE);
  float var = s2 * (1.f / EE) - mu * mu;
  float rs = rsqrtf(var + 1e-5f);
  float* orow = out + (size_t)row * EE;
#pragma unroll
  for (int i = 0; i < 6; ++i) {
    int e = lane + 64 * i;
    orow[e] = (v[i] - mu) * rs * g[e] + b[e];
  }
}

// ---------------- fp32 tiled GEMM: C = [res +] [relu](A@W + bias) ----------------
// A[M,K], W[K,N] row-major. M%64==0, N%64==0, K%32==0.
template <bool BIAS, bool RELU, bool RES>
__global__ __launch_bounds__(256)
void gemm_f32(const float* __restrict__ A, const float* __restrict__ W,
              const float* __restrict__ bias, float* __restrict__ C,
              int M, int N, int K) {
  constexpr int BM = 64, BN = 64, BK = 32;
  __shared__ float As[BK][BM];
  __shared__ float Ws[BK][BN];
  const int tid = threadIdx.x;
  const int bm = blockIdx.y * BM;
  const int bn = blockIdx.x * BN;
  const int tn = tid & 15, tm = tid >> 4;
  float acc[4][4] = {};

  for (int k0 = 0; k0 < K; k0 += BK) {
#pragma unroll
    for (int p = 0; p < 2; ++p) {
      int f = tid + p * 256;
      int row = f >> 3;
      int kc = (f & 7) << 2;
      float4 a4 = *(const float4*)&A[(size_t)(bm + row) * K + k0 + kc];
      As[kc + 0][row] = a4.x;
      As[kc + 1][row] = a4.y;
      As[kc + 2][row] = a4.z;
      As[kc + 3][row] = a4.w;
      int kr = f >> 4;
      int nc = (f & 15) << 2;
      *(float4*)&Ws[kr][nc] = *(const float4*)&W[(size_t)(k0 + kr) * N + bn + nc];
    }
    __syncthreads();
#pragma unroll
    for (int kk = 0; kk < BK; ++kk) {
      float4 av = *(const float4*)&As[kk][tm << 2];
      float4 bv = *(const float4*)&Ws[kk][tn << 2];
      acc[0][0] += av.x * bv.x; acc[0][1] += av.x * bv.y; acc[0][2] += av.x * bv.z; acc[0][3] += av.x * bv.w;
      acc[1][0] += av.y * bv.x; acc[1][1] += av.y * bv.y; acc[1][2] += av.y * bv.z; acc[1][3] += av.y * bv.w;
      acc[2][0] += av.z * bv.x; acc[2][1] += av.z * bv.y; acc[2][2] += av.z * bv.z; acc[2][3] += av.z * bv.w;
      acc[3][0] += av.w * bv.x; acc[3][1] += av.w * bv.y; acc[3][2] += av.w * bv.z; acc[3][3] += av.w * bv.w;
    }
    __syncthreads();
  }

  const int row = bm + (tm << 2);
  const int col = bn + (tn << 2);
#pragma unroll
  for (int i = 0; i < 4; ++i) {
    float4 r;
    r.x = acc[i][0]; r.y = acc[i][1]; r.z = acc[i][2]; r.w = acc[i][3];
    if constexpr (BIAS) {
      float4 b4 = *(const float4*)&bias[col];
      r.x += b4.x; r.y += b4.y; r.z += b4.z; r.w += b4.w;
    }
    if constexpr (RELU) {
      r.x = fmaxf(r.x, 0.f); r.y = fmaxf(r.y, 0.f);
      r.z = fmaxf(r.z, 0.f); r.w = fmaxf(r.w, 0.f);
    }
    if constexpr (RES) {
      float4 c4 = *(const float4*)&C[(size_t)(row + i) * N + col];
      r.x += c4.x; r.y += c4.y; r.z += c4.z; r.w += c4.w;
    }
    *(float4*)&C[(size_t)(row + i) * N + col] = r;
  }
}

// ---------------- attention: one block per (seq,h); K bf16 in static LDS ----------------
// q,k,v,o are chunk-local [R, E] with layout [(b*T+t)*E + h*64 + d]
__global__ __launch_bounds__(256)
void attn_kernel(const float* __restrict__ q, const float* __restrict__ k,
                 const float* __restrict__ v, float* __restrict__ o) {
  __shared__ __hip_bfloat16 Ks[256][66];   // 33792 B, pad 66 -> stride 33 words
  __shared__ float att[4][256];            // 4096 B, per-wave row
  int bh = blockIdx.x;
  int bloc = bh / HH, hh = bh % HH;
  const size_t base = ((size_t)bloc * TT) * EE + hh * 64;
  int tid = threadIdx.x;

  for (int f = tid; f < 256 * 16; f += 256) {
    int s = f >> 4, c4 = (f & 15) << 2;
    float4 k4 = *(const float4*)&k[base + (size_t)s * EE + c4];
    Ks[s][c4 + 0] = __float2bfloat16(k4.x);
    Ks[s][c4 + 1] = __float2bfloat16(k4.y);
    Ks[s][c4 + 2] = __float2bfloat16(k4.z);
    Ks[s][c4 + 3] = __float2bfloat16(k4.w);
  }
  __syncthreads();

  int w = tid >> 6, lane = tid & 63;

  for (int it = 0; it < 64; ++it) {
    int t = it * 4 + w;                       // interleaved rows: load-balanced
    const float* qrow = q + base + (size_t)t * EE;
    float sc[4] = {0.f, 0.f, 0.f, 0.f};
#pragma unroll 4
    for (int d = 0; d < 64; ++d) {
      float qd = qrow[d];                     // uniform address, broadcast
#pragma unroll
      for (int i = 0; i < 4; ++i)
        sc[i] += qd * __bfloat162float(Ks[i * 64 + lane][d]);
    }
    float m = -INFINITY;
#pragma unroll
    for (int i = 0; i < 4; ++i) {
      int s = i * 64 + lane;
      sc[i] = (s <= t) ? sc[i] * 0.125f : -INFINITY;
      m = fmaxf(m, sc[i]);
    }
#pragma unroll
    for (int off = 32; off; off >>= 1) m = fmaxf(m, __shfl_xor(m, off));
    float p[4], ps = 0.f;
#pragma unroll
    for (int i = 0; i < 4; ++i) {
      p[i] = (sc[i] == -INFINITY) ? 0.f : expf(sc[i] - m);
      ps += p[i];
    }
#pragma unroll
    for (int off = 32; off; off >>= 1) ps += __shfl_xor(ps, off);
    float inv = 1.f / ps;
#pragma unroll
    for (int i = 0; i < 4; ++i) att[w][i * 64 + lane] = p[i] * inv;
    __syncthreads();

    float outv = 0.f;
    const float* vcol = v + base + lane;       // V read from global (L2/L3-hot)
    int s = 0;
    for (; s + 8 <= t + 1; s += 8) {
      float a0 = att[w][s + 0], a1 = att[w][s + 1], a2 = att[w][s + 2], a3 = att[w][s + 3];
      float a4 = att[w][s + 4], a5 = att[w][s + 5], a6 = att[w][s + 6], a7 = att[w][s + 7];
      outv += a0 * vcol[(size_t)(s + 0) * EE] + a1 * vcol[(size_t)(s + 1) * EE] +
              a2 * vcol[(size_t)(s + 2) * EE] + a3 * vcol[(size_t)(s + 3) * EE] +
              a4 * vcol[(size_t)(s + 4) * EE] + a5 * vcol[(size_t)(s + 5) * EE] +
              a6 * vcol[(size_t)(s + 6) * EE] + a7 * vcol[(size_t)(s + 7) * EE];
    }
    for (; s <= t; ++s) outv += att[w][s] * vcol[(size_t)s * EE];
    o[base + (size_t)t * EE + lane] = outv;
    __syncthreads();
  }
}

// -------- head: logits = xf @ Wh + bh; log_softmax; NLL mean (atomic) --------
// xf, targets, logits are chunk-local (pre-offset pointers).
__global__ __launch_bounds__(256)
void head_loss_kernel(const float* __restrict__ xf, const float* __restrict__ Wh,
                      const float* __restrict__ bh, const int* __restrict__ targets,
                      float* __restrict__ logits, float* __restrict__ loss_acc) {
  int wid = threadIdx.x >> 6, lane = threadIdx.x & 63;
  int r = blockIdx.x * 4 + wid;
  const float* xr = xf + (size_t)r * EE;
  float acc = bh[lane];      // column = lane (0..63)
  float acc64 = bh[64];      // column 64, computed redundantly by all lanes
#pragma unroll 4
  for (int e = 0; e < EE; ++e) {
    float xv = xr[e];                         // uniform broadcast
    acc += xv * Wh[e * VV + lane];
    acc64 += xv * Wh[e * VV + 64];
  }
  float m = fmaxf(acc, acc64);
#pragma unroll
  for (int off = 32; off; off >>= 1) m = fmaxf(m, __shfl_xor(m, off));
  float pe = expf(acc - m);
  float s = pe;
#pragma unroll
  for (int off = 32; off; off >>= 1) s += __shfl_xor(s, off);
  s += expf(acc64 - m);
  float lse = m + logf(s);

  float* lrow = logits + (size_t)r * VV;
  lrow[lane] = acc;
  if (lane == 0) lrow[64] = acc64;

  int t = targets[r];
  float tv;
  if (t < 64) tv = __shfl(acc, t);
  else        tv = acc64;
  float nll = lse - tv;
  if (lane == 0) atomicAdd(loss_acc, nll * (1.f / BT));
}

// ---------------- launcher ----------------
extern "C" void kernel_launch(void* const* d_in, const int* in_sizes, int n_in,
                              void* d_out, int out_size, void* d_ws, size_t ws_size,
                              hipStream_t stream) {
  const int* inputs = (const int*)d_in[0];
  const int* targets = (const int*)d_in[1];
  const float* tok_emb = (const float*)d_in[2];
  const float* pos_emb = (const float*)d_in[3];
  const float* Wq = (const float*)d_in[4];
  const float* Wk = (const float*)d_in[5];
  const float* Wv = (const float*)d_in[6];
  const float* Wo = (const float*)d_in[7];
  const float* bo = (const float*)d_in[8];
  const float* ln1_g = (const float*)d_in[9];
  const float* ln1_b = (const float*)d_in[10];
  const float* W1 = (const float*)d_in[11];
  const float* b1 = (const float*)d_in[12];
  const float* W2 = (const float*)d_in[13];
  const float* b2 = (const float*)d_in[14];
  const float* ln2_g = (const float*)d_in[15];
  const float* ln2_b = (const float*)d_in[16];
  const float* lnf_g = (const float*)d_in[17];
  const float* lnf_b = (const float*)d_in[18];
  const float* Wh = (const float*)d_in[19];
  const float* bh = (const float*)d_in[20];

  float* logits = (float*)d_out;
  float* loss = logits + (size_t)BT * VV;

  const size_t LEE = (size_t)LL * EE * EE;   // 884736 floats per weight set

  // chunk size: c sequences at a time, largest power of two whose footprint fits ws
  int c = 64;
  while (c > 1 &&
         3 * LEE * sizeof(float) + (size_t)c * 256 * (2 * EE + FF) * sizeof(float) > ws_size)
    c >>= 1;
  const int R = c * TT;                      // rows per chunk
  const int nch = BB / c;
  const size_t RE = (size_t)R * EE;

  float* qT = (float*)d_ws;
  float* kT = qT + LEE;
  float* vT = kT + LEE;
  float* x = vT + LEE;
  float* h = x + RE;
  float* big = h + RE;                       // q,k,v (3*RE) or mid (R*FF); FF >= 3*EE
  float* qb = big;
  float* kb = big + RE;
  float* vb = big + 2 * RE;
  float* mid = big;

  hipMemsetAsync(loss, 0, sizeof(float), stream);
  transpose_qkv_kernel<<<(int)(LL * EE * EE / 256), 256, 0, stream>>>(Wq, Wk, Wv, qT, kT, vT);

  dim3 g66(EE / 64, R / 64);
  dim3 gF(FF / 64, R / 64);

  for (int ch = 0; ch < nch; ++ch) {
    const size_t r0 = (size_t)ch * R;
    embed_kernel<<<R * (EE / 4) / 256, 256, 0, stream>>>(inputs + r0, tok_emb, pos_emb, x);
    for (int l = 0; l < LL; ++l) {
      layernorm_384<<<R / 4, 256, 0, stream>>>(x, ln1_g + l * EE, ln1_b + l * EE, h);
      gemm_f32<false, false, false><<<g66, 256, 0, stream>>>(h, qT + (size_t)l * EE * EE, nullptr, qb, R, EE, EE);
      gemm_f32<false, false, false><<<g66, 256, 0, stream>>>(h, kT + (size_t)l * EE * EE, nullptr, kb, R, EE, EE);
      gemm_f32<false, false, false><<<g66, 256, 0, stream>>>(h, vT + (size_t)l * EE * EE, nullptr, vb, R, EE, EE);
      attn_kernel<<<c * HH, 256, 0, stream>>>(qb, kb, vb, h);
      gemm_f32<true, false, true><<<g66, 256, 0, stream>>>(h, Wo + (size_t)l * EE * EE, bo + l * EE, x, R, EE, EE);
      layernorm_384<<<R / 4, 256, 0, stream>>>(x, ln2_g + l * EE, ln2_b + l * EE, h);
      gemm_f32<true, true, false><<<gF, 256, 0, stream>>>(h, W1 + (size_t)l * EE * FF, b1 + l * FF, mid, R, FF, EE);
      gemm_f32<true, false, true><<<g66, 256, 0, stream>>>(mid, W2 + (size_t)l * FF * EE, b2 + l * EE, x, R, EE, FF);
    }
    layernorm_384<<<R / 4, 256, 0, stream>>>(x, lnf_g, lnf_b, h);
    head_loss_kernel<<<R / 4, 256, 0, stream>>>(h, Wh, bh, targets + r0, logits + r0 * VV, loss);
  }
}

// Round 3
// 8938.971 us; speedup vs baseline: 3.6687x; 3.6687x over previous
//
#include <hip/hip_runtime.h>
#include <math.h>

#define LL 6
#define HH 6
#define DD 64
#define EE 384
#define FF 1536
#define TT 256
#define BB 256
#define VV 65
constexpr int BT = BB * TT;                 // 65536 rows total

typedef __attribute__((ext_vector_type(8))) short s16x8;   // 8 bf16 (4 VGPR)
typedef __attribute__((ext_vector_type(4))) float f32x4;
typedef __attribute__((ext_vector_type(4))) unsigned int u32x4;
typedef unsigned int uint;
typedef unsigned short ushort_t;

__device__ __forceinline__ float uaf(uint u) { union { uint u; float f; } c; c.u = u; return c.f; }
__device__ __forceinline__ ushort_t f2b(float f) {
  union { float f; uint u; } c; c.f = f;
  uint r = c.u + 0x7fffu + ((c.u >> 16) & 1u);          // RNE
  return (ushort_t)(r >> 16);
}
__device__ __forceinline__ float b2f(ushort_t b) { return uaf((uint)b << 16); }

// ---------------- embed: x = tok_emb[inputs] + pos_emb (chunk rows) ----------------
__global__ __launch_bounds__(256)
void embed_kernel(const int* __restrict__ inp, const float* __restrict__ tok,
                  const float* __restrict__ pos, float* __restrict__ x) {
  int idx = blockIdx.x * 256 + threadIdx.x;      // over R*EE/4, exact grid
  int e4 = idx % (EE / 4);
  int r = idx / (EE / 4);
  int t = r % TT;
  int tk = inp[r];
  float4 a = ((const float4*)tok)[tk * (EE / 4) + e4];
  float4 p = ((const float4*)pos)[t * (EE / 4) + e4];
  float4 o;
  o.x = a.x + p.x; o.y = a.y + p.y; o.z = a.z + p.z; o.w = a.w + p.w;
  ((float4*)x)[idx] = o;
}

// ------- pack QKV weights: [l][h][e][d] f32 -> bf16 [l][n=1152][k=384] (W^T) -------
__global__ __launch_bounds__(256)
void pack_qkv(const float* __restrict__ Wq, const float* __restrict__ Wk,
              const float* __restrict__ Wv, ushort_t* __restrict__ dst) {
  int idx = blockIdx.x * 256 + threadIdx.x;      // over LL*1152*384
  int l = idx / (1152 * 384);
  int r = idx % (1152 * 384);
  int n = r / 384;
  int k = r % 384;
  int which = n / 384 == 0 ? (n >> 7) / 3 : 0;   // avoid div: n in [0,1152)
  which = n / 384;                                // 0:q 1:k 2:v
  int hd = n % 384;
  int h = hd >> 6, d = hd & 63;
  const float* src = which == 0 ? Wq : (which == 1 ? Wk : Wv);
  dst[idx] = f2b(src[((size_t)(l * HH + h) * EE + k) * DD + d]);
}

// ------- pack generic weight: [l][k=Kd][n=Nd] f32 -> bf16 [l][n][k] (W^T) -------
__global__ __launch_bounds__(256)
void pack_wt(const float* __restrict__ src, ushort_t* __restrict__ dst, int Kd, int Nd) {
  int idx = blockIdx.x * 256 + threadIdx.x;      // over LL*Kd*Nd
  int l = idx / (Kd * Nd);
  int r = idx % (Kd * Nd);
  int n = r / Kd;
  int k = r % Kd;
  dst[idx] = f2b(src[((size_t)l * Kd + k) * Nd + n]);
}

// ---------------- layernorm over E=384, one wave per row ----------------
template <int BF16OUT>
__global__ __launch_bounds__(256)
void layernorm_384(const float* __restrict__ x, const float* __restrict__ g,
                   const float* __restrict__ b, void* __restrict__ outp) {
  int wid = threadIdx.x >> 6, lane = threadIdx.x & 63;
  int row = blockIdx.x * 4 + wid;
  const float* xr = x + (size_t)row * EE;
  float v[6];
  float s = 0.f, s2 = 0.f;
#pragma unroll
  for (int i = 0; i < 6; ++i) {
    v[i] = xr[lane + 64 * i];
    s += v[i];
    s2 += v[i] * v[i];
  }
#pragma unroll
  for (int off = 32; off; off >>= 1) {
    s += __shfl_xor(s, off);
    s2 += __shfl_xor(s2, off);
  }
  float mu = s * (1.f / EE);
  float var = s2 * (1.f / EE) - mu * mu;
  float rs = rsqrtf(var + 1e-5f);
#pragma unroll
  for (int i = 0; i < 6; ++i) {
    int e = lane + 64 * i;
    float val = (v[i] - mu) * rs * g[e] + b[e];
    if constexpr (BF16OUT) ((ushort_t*)outp)[(size_t)row * EE + e] = f2b(val);
    else                    ((float*)outp)[(size_t)row * EE + e] = val;
  }
}

// ------------- bf16 MFMA GEMM: out = [res +] [relu](A@W + bias) -------------
// A[M,K] bf16 row-major, Wt[N,K] bf16 (i.e. W^T). M%128==0, N%128==0, K%32==0.
// RES: Cf[M,N] f32 += acc+bias.  else: Cb[M,N] bf16 = (relu)(acc+bias).
template <bool BIAS, bool RELU, bool RES>
__global__ __launch_bounds__(256)
void gemm_bf16(const ushort_t* __restrict__ A, const ushort_t* __restrict__ Wt,
               const float* __restrict__ bias, ushort_t* __restrict__ Cb,
               float* __restrict__ Cf, int M, int N, int K) {
  __shared__ ushort_t As[128 * 32];
  __shared__ ushort_t Bs[128 * 32];
  const int tid = threadIdx.x;
  const int bn = blockIdx.x * 128, bm = blockIdx.y * 128;
  const int w = tid >> 6, lane = tid & 63;
  const int wr = (w >> 1) * 64, wc = (w & 1) * 64;    // wave tile origin
  const int fr = lane & 15, fq = lane >> 4;           // fragment row/col, k-quarter
  f32x4 acc[4][4] = {};

  const int srow = tid >> 2, scol = (tid & 3) * 8;    // staging: 16B per thread, 2 rows-waves
  const ushort_t* Ag = A + (size_t)(bm + srow) * K + scol;
  const ushort_t* Bg = Wt + (size_t)(bn + srow) * K + scol;
  const size_t rstep = (size_t)64 * K;
  ushort_t* AsW = As + srow * 32 + scol;
  ushort_t* BsW = Bs + srow * 32 + scol;

  for (int k0 = 0; k0 < K; k0 += 32) {
    s16x8 a0 = *(const s16x8*)(Ag + k0);
    s16x8 a1 = *(const s16x8*)(Ag + rstep + k0);
    s16x8 b0 = *(const s16x8*)(Bg + k0);
    s16x8 b1 = *(const s16x8*)(Bg + rstep + k0);
    __syncthreads();
    *(s16x8*)AsW = a0;
    *(s16x8*)(AsW + 64 * 32) = a1;
    *(s16x8*)BsW = b0;
    *(s16x8*)(BsW + 64 * 32) = b1;
    __syncthreads();
    s16x8 afr[4], bfr[4];
#pragma unroll
    for (int m = 0; m < 4; ++m)
      afr[m] = *(const s16x8*)(As + (wr + m * 16 + fr) * 32 + fq * 8);
#pragma unroll
    for (int n = 0; n < 4; ++n)
      bfr[n] = *(const s16x8*)(Bs + (wc + n * 16 + fr) * 32 + fq * 8);
#pragma unroll
    for (int m = 0; m < 4; ++m)
#pragma unroll
      for (int n = 0; n < 4; ++n)
        acc[m][n] = __builtin_amdgcn_mfma_f32_16x16x32_bf16(afr[m], bfr[n], acc[m][n], 0, 0, 0);
  }

  // epilogue: D row = (lane>>4)*4 + j, col = lane&15 (m89/m91-verified layout)
  const int r0 = bm + wr + fq * 4;
  const int c0 = bn + wc + fr;
#pragma unroll
  for (int n = 0; n < 4; ++n) {
    const int col = c0 + n * 16;
    const float bv = BIAS ? bias[col] : 0.f;
#pragma unroll
    for (int m = 0; m < 4; ++m) {
      const int row = r0 + m * 16;
#pragma unroll
      for (int j = 0; j < 4; ++j) {
        float vv = acc[m][n][j] + bv;
        if constexpr (RELU) vv = fmaxf(vv, 0.f);
        if constexpr (RES) Cf[(size_t)(row + j) * N + col] += vv;
        else               Cb[(size_t)(row + j) * N + col] = f2b(vv);
      }
    }
  }
}

// ------------- attention: block = (causal-quarter, seq, head); K bf16 in LDS -------------
// qkv: [R][1152] bf16 (q|k|v each [384] = h*64+d). o: [R][384] bf16.
__global__ __launch_bounds__(256)
void attn_kernel(const ushort_t* __restrict__ qkv, ushort_t* __restrict__ o, int cseq) {
  __shared__ ushort_t Ks[256 * 66];          // pad 66: conflict-free uint reads
  __shared__ float att[4][256];              // per-wave row
  const int tid = threadIdx.x;
  const int nb = cseq * HH;
  const int qtr = 3 - blockIdx.x / nb;       // heavy quarters dispatched first
  const int sh = blockIdx.x % nb;
  const int seq = sh / HH, hh = sh % HH;
  const int ng = qtr + 1;                    // k-groups of 64 needed
  const int brow = seq * TT;

  for (int f = tid; f < ng * 2048; f += 256) {
    int s = f >> 5, dp = f & 31;
    *(uint*)&Ks[s * 66 + dp * 2] =
        *(const uint*)&qkv[(size_t)(brow + s) * 1152 + 384 + hh * 64 + dp * 2];
  }
  __syncthreads();

  const int w = tid >> 6, lane = tid & 63;
  const ushort_t* vbase = qkv + (size_t)brow * 1152 + 768 + hh * 64 + lane;

  for (int it = 0; it < 16; ++it) {
    const int t = qtr * 64 + it * 4 + w;     // this wave's query row
    const uint* qrow = (const uint*)(qkv + (size_t)(brow + t) * 1152 + hh * 64);
    u32x4 qv[8];
#pragma unroll
    for (int g = 0; g < 8; ++g) qv[g] = ((const u32x4*)qrow)[g];

    float sc[4] = {0.f, 0.f, 0.f, 0.f};
#pragma unroll
    for (int i = 0; i < 4; ++i) {
      if (i <= qtr) {                        // uniform branch per block
        float s0 = 0.f;
#pragma unroll
        for (int dp = 0; dp < 32; ++dp) {
          uint qp = qv[dp >> 2][dp & 3];
          uint kp = *(const uint*)&Ks[(i * 64 + lane) * 66 + dp * 2];
          s0 += uaf(qp << 16) * uaf(kp << 16) +
                uaf(qp & 0xffff0000u) * uaf(kp & 0xffff0000u);
        }
        sc[i] = s0;
      }
    }

    float m = -INFINITY;
    float sm[4];
#pragma unroll
    for (int i = 0; i < 4; ++i) {
      int s = i * 64 + lane;
      sm[i] = (i <= qtr && s <= t) ? sc[i] * 0.125f : -INFINITY;
      m = fmaxf(m, sm[i]);
    }
#pragma unroll
    for (int off = 32; off; off >>= 1) m = fmaxf(m, __shfl_xor(m, off));
    float p[4], ps = 0.f;
#pragma unroll
    for (int i = 0; i < 4; ++i) {
      p[i] = (sm[i] == -INFINITY) ? 0.f : __expf(sm[i] - m);
      ps += p[i];
    }
#pragma unroll
    for (int off = 32; off; off >>= 1) ps += __shfl_xor(ps, off);
    float inv = 1.f / ps;
#pragma unroll
    for (int i = 0; i < 4; ++i) att[w][i * 64 + lane] = p[i] * inv;
    asm volatile("s_waitcnt lgkmcnt(0)" ::: "memory");   // per-wave LDS write->read

    float outv = 0.f;
    int s = 0;
    for (; s + 8 <= t + 1; s += 8) {
      outv += att[w][s + 0] * b2f(vbase[(size_t)(s + 0) * 1152]) +
              att[w][s + 1] * b2f(vbase[(size_t)(s + 1) * 1152]) +
              att[w][s + 2] * b2f(vbase[(size_t)(s + 2) * 1152]) +
              att[w][s + 3] * b2f(vbase[(size_t)(s + 3) * 1152]) +
              att[w][s + 4] * b2f(vbase[(size_t)(s + 4) * 1152]) +
              att[w][s + 5] * b2f(vbase[(size_t)(s + 5) * 1152]) +
              att[w][s + 6] * b2f(vbase[(size_t)(s + 6) * 1152]) +
              att[w][s + 7] * b2f(vbase[(size_t)(s + 7) * 1152]);
    }
    for (; s <= t; ++s) outv += att[w][s] * b2f(vbase[(size_t)s * 1152]);
    o[(size_t)(brow + t) * 384 + hh * 64 + lane] = f2b(outv);
  }
}

// -------- head: logits = xf @ Wh + bh; log_softmax; NLL mean (atomic) --------
__global__ __launch_bounds__(256)
void head_loss_kernel(const float* __restrict__ xf, const float* __restrict__ Wh,
                      const float* __restrict__ bh, const int* __restrict__ targets,
                      float* __restrict__ logits, float* __restrict__ loss_acc) {
  int wid = threadIdx.x >> 6, lane = threadIdx.x & 63;
  int r = blockIdx.x * 4 + wid;
  const float* xr = xf + (size_t)r * EE;
  float acc = bh[lane];
  float acc64 = bh[64];
#pragma unroll 4
  for (int e = 0; e < EE; ++e) {
    float xv = xr[e];
    acc += xv * Wh[e * VV + lane];
    acc64 += xv * Wh[e * VV + 64];
  }
  float m = fmaxf(acc, acc64);
#pragma unroll
  for (int off = 32; off; off >>= 1) m = fmaxf(m, __shfl_xor(m, off));
  float pe = expf(acc - m);
  float s = pe;
#pragma unroll
  for (int off = 32; off; off >>= 1) s += __shfl_xor(s, off);
  s += expf(acc64 - m);
  float lse = m + logf(s);

  float* lrow = logits + (size_t)r * VV;
  lrow[lane] = acc;
  if (lane == 0) lrow[64] = acc64;

  int t = targets[r];
  float tv;
  if (t < 64) tv = __shfl(acc, t);
  else        tv = acc64;
  float nll = lse - tv;
  if (lane == 0) atomicAdd(loss_acc, nll * (1.f / BT));
}

// ---------------- launcher ----------------
extern "C" void kernel_launch(void* const* d_in, const int* in_sizes, int n_in,
                              void* d_out, int out_size, void* d_ws, size_t ws_size,
                              hipStream_t stream) {
  const int* inputs = (const int*)d_in[0];
  const int* targets = (const int*)d_in[1];
  const float* tok_emb = (const float*)d_in[2];
  const float* pos_emb = (const float*)d_in[3];
  const float* Wq = (const float*)d_in[4];
  const float* Wk = (const float*)d_in[5];
  const float* Wv = (const float*)d_in[6];
  const float* Wo = (const float*)d_in[7];
  const float* bo = (const float*)d_in[8];
  const float* ln1_g = (const float*)d_in[9];
  const float* ln1_b = (const float*)d_in[10];
  const float* W1 = (const float*)d_in[11];
  const float* b1 = (const float*)d_in[12];
  const float* W2 = (const float*)d_in[13];
  const float* b2 = (const float*)d_in[14];
  const float* ln2_g = (const float*)d_in[15];
  const float* ln2_b = (const float*)d_in[16];
  const float* lnf_g = (const float*)d_in[17];
  const float* lnf_b = (const float*)d_in[18];
  const float* Wh = (const float*)d_in[19];
  const float* bh = (const float*)d_in[20];

  float* logits = (float*)d_out;
  float* loss = logits + (size_t)BT * VV;

  auto al = [](size_t b) { return (b + 255) & ~(size_t)255; };
  const size_t wq_b = al((size_t)LL * 1152 * 384 * 2);
  const size_t wo_b = al((size_t)LL * 384 * 384 * 2);
  const size_t w1_b = al((size_t)LL * 1536 * 384 * 2);
  const size_t wfix = wq_b + wo_b + 2 * w1_b;

  int c = BB;                                  // sequences per chunk
  while (c > 1 && wfix + (size_t)c * 256 * 6144 > ws_size) c >>= 1;
  const int R = c * TT;
  const int nch = BB / c;

  char* p = (char*)d_ws;
  ushort_t* wqkv = (ushort_t*)p; p += wq_b;
  ushort_t* wot  = (ushort_t*)p; p += wo_b;
  ushort_t* w1t  = (ushort_t*)p; p += w1_b;
  ushort_t* w2t  = (ushort_t*)p; p += w1_b;
  float* x = (float*)p;          p += (size_t)R * 1536;   // [R,384] f32
  ushort_t* hb = (ushort_t*)p;   p += (size_t)R * 768;    // [R,384] bf16
  ushort_t* ob = (ushort_t*)p;   p += (size_t)R * 768;    // [R,384] bf16
  ushort_t* un = (ushort_t*)p;                            // R*3072 B union
  ushort_t* qkvb = un;                                    // [R,1152] bf16
  ushort_t* midb = un;                                    // [R,1536] bf16
  float* hf = (float*)un;                                 // [R,384] f32 (head)

  hipMemsetAsync(loss, 0, 4, stream);
  pack_qkv<<<LL * 1152 * 384 / 256, 256, 0, stream>>>(Wq, Wk, Wv, wqkv);
  pack_wt<<<LL * 384 * 384 / 256, 256, 0, stream>>>(Wo, wot, 384, 384);
  pack_wt<<<LL * 384 * 1536 / 256, 256, 0, stream>>>(W1, w1t, 384, 1536);
  pack_wt<<<LL * 1536 * 384 / 256, 256, 0, stream>>>(W2, w2t, 1536, 384);

  for (int ch = 0; ch < nch; ++ch) {
    const size_t r0 = (size_t)ch * R;
    embed_kernel<<<R * 96 / 256, 256, 0, stream>>>(inputs + r0, tok_emb, pos_emb, x);
    for (int l = 0; l < LL; ++l) {
      layernorm_384<1><<<R / 4, 256, 0, stream>>>(x, ln1_g + l * EE, ln1_b + l * EE, hb);
      gemm_bf16<false, false, false><<<dim3(9, R / 128), 256, 0, stream>>>(
          hb, wqkv + (size_t)l * 1152 * 384, nullptr, qkvb, nullptr, R, 1152, 384);
      attn_kernel<<<c * HH * 4, 256, 0, stream>>>(qkvb, ob, c);
      gemm_bf16<true, false, true><<<dim3(3, R / 128), 256, 0, stream>>>(
          ob, wot + (size_t)l * 384 * 384, bo + l * EE, nullptr, x, R, 384, 384);
      layernorm_384<1><<<R / 4, 256, 0, stream>>>(x, ln2_g + l * EE, ln2_b + l * EE, hb);
      gemm_bf16<true, true, false><<<dim3(12, R / 128), 256, 0, stream>>>(
          hb, w1t + (size_t)l * 1536 * 384, b1 + l * FF, midb, nullptr, R, 1536, 384);
      gemm_bf16<true, false, true><<<dim3(3, R / 128), 256, 0, stream>>>(
          midb, w2t + (size_t)l * 384 * 1536, b2 + l * EE, nullptr, x, R, 384, 1536);
    }
    layernorm_384<0><<<R / 4, 256, 0, stream>>>(x, lnf_g, lnf_b, hf);
    head_loss_kernel<<<R / 4, 256, 0, stream>>>(hf, Wh, bh, targets + r0,
                                                logits + r0 * VV, loss);
  }
}

// Round 4
// 8501.192 us; speedup vs baseline: 3.8577x; 1.0515x over previous
//
#include <hip/hip_runtime.h>
#include <math.h>

#define LL 6
#define HH 6
#define DD 64
#define EE 384
#define FF 1536
#define TT 256
#define BB 256
#define VV 65
constexpr int BT = BB * TT;                 // 65536 rows total

typedef __attribute__((ext_vector_type(8))) short s16x8;   // 8 bf16 (4 VGPR)
typedef __attribute__((ext_vector_type(4))) float f32x4;
typedef __attribute__((ext_vector_type(4))) unsigned int u32x4;
typedef unsigned int uint;
typedef unsigned short ushort_t;

__device__ __forceinline__ float uaf(uint u) { union { uint u; float f; } c; c.u = u; return c.f; }
__device__ __forceinline__ ushort_t f2b(float f) {
  union { float f; uint u; } c; c.f = f;
  uint r = c.u + 0x7fffu + ((c.u >> 16) & 1u);          // RNE
  return (ushort_t)(r >> 16);
}
__device__ __forceinline__ float b2f(ushort_t b) { return uaf((uint)b << 16); }

__device__ __forceinline__ void gload_lds16(const void* g, void* l) {
  __builtin_amdgcn_global_load_lds(
      (const __attribute__((address_space(1))) unsigned int*)g,
      (__attribute__((address_space(3))) unsigned int*)l, 16, 0, 0);
}

// ---------------- embed: x = tok_emb[inputs] + pos_emb (chunk rows) ----------------
__global__ __launch_bounds__(256)
void embed_kernel(const int* __restrict__ inp, const float* __restrict__ tok,
                  const float* __restrict__ pos, float* __restrict__ x) {
  int idx = blockIdx.x * 256 + threadIdx.x;      // over R*EE/4, exact grid
  int e4 = idx % (EE / 4);
  int r = idx / (EE / 4);
  int t = r % TT;
  int tk = inp[r];
  float4 a = ((const float4*)tok)[tk * (EE / 4) + e4];
  float4 p = ((const float4*)pos)[t * (EE / 4) + e4];
  float4 o;
  o.x = a.x + p.x; o.y = a.y + p.y; o.z = a.z + p.z; o.w = a.w + p.w;
  ((float4*)x)[idx] = o;
}

// ------- pack QKV weights: [l][h][e][d] f32 -> bf16 [l][n=1152][k=384] (W^T) -------
__global__ __launch_bounds__(256)
void pack_qkv(const float* __restrict__ Wq, const float* __restrict__ Wk,
              const float* __restrict__ Wv, ushort_t* __restrict__ dst) {
  int idx = blockIdx.x * 256 + threadIdx.x;      // over LL*1152*384
  int l = idx / (1152 * 384);
  int r = idx % (1152 * 384);
  int n = r / 384;
  int k = r % 384;
  int which = n / 384;                            // 0:q 1:k 2:v
  int hd = n % 384;
  int h = hd >> 6, d = hd & 63;
  const float* src = which == 0 ? Wq : (which == 1 ? Wk : Wv);
  dst[idx] = f2b(src[((size_t)(l * HH + h) * EE + k) * DD + d]);
}

// ------- pack generic weight: [l][k=Kd][n=Nd] f32 -> bf16 [l][n][k] (W^T) -------
__global__ __launch_bounds__(256)
void pack_wt(const float* __restrict__ src, ushort_t* __restrict__ dst, int Kd, int Nd) {
  int idx = blockIdx.x * 256 + threadIdx.x;      // over LL*Kd*Nd
  int l = idx / (Kd * Nd);
  int r = idx % (Kd * Nd);
  int n = r / Kd;
  int k = r % Kd;
  dst[idx] = f2b(src[((size_t)l * Kd + k) * Nd + n]);
}

// ------- pack head: Wh [k=384][v=65] f32 -> bf16 [n=128][k=384], zero-pad n>=65 -------
__global__ __launch_bounds__(256)
void pack_head(const float* __restrict__ Wh, ushort_t* __restrict__ dst) {
  int idx = blockIdx.x * 256 + threadIdx.x;      // over 128*384
  int n = idx / 384, k = idx % 384;
  dst[idx] = (n < VV) ? f2b(Wh[(size_t)k * VV + n]) : (ushort_t)0;
}

// ---------------- layernorm over E=384, one wave per row ----------------
template <int BF16OUT>
__global__ __launch_bounds__(256)
void layernorm_384(const float* __restrict__ x, const float* __restrict__ g,
                   const float* __restrict__ b, void* __restrict__ outp) {
  int wid = threadIdx.x >> 6, lane = threadIdx.x & 63;
  int row = blockIdx.x * 4 + wid;
  const float* xr = x + (size_t)row * EE;
  float v[6];
  float s = 0.f, s2 = 0.f;
#pragma unroll
  for (int i = 0; i < 6; ++i) {
    v[i] = xr[lane + 64 * i];
    s += v[i];
    s2 += v[i] * v[i];
  }
#pragma unroll
  for (int off = 32; off; off >>= 1) {
    s += __shfl_xor(s, off);
    s2 += __shfl_xor(s2, off);
  }
  float mu = s * (1.f / EE);
  float var = s2 * (1.f / EE) - mu * mu;
  float rs = rsqrtf(var + 1e-5f);
#pragma unroll
  for (int i = 0; i < 6; ++i) {
    int e = lane + 64 * i;
    float val = (v[i] - mu) * rs * g[e] + b[e];
    if constexpr (BF16OUT) ((ushort_t*)outp)[(size_t)row * EE + e] = f2b(val);
    else                    ((float*)outp)[(size_t)row * EE + e] = val;
  }
}

// ------------- bf16 MFMA GEMM: out = [res +] [relu](A@W + bias) -------------
// A[M,K] bf16 row-major, Wt[N,K] bf16 (W^T). M%128==0, N%128==0, K%32==0.
// 1-D grid (nwg = (N/128)*(M/128)), bijective XCD swizzle, n-tile fast.
// Staging: global_load_lds w16, slot-swizzled LDS (slot = fq ^ ((row>>1)&3)).
// HEAD: write f32 logits, stride VV, cols<VV only.
// RES: Cf[M,N] f32 += acc+bias.  else: Cb[M,N] bf16 = (relu)(acc+bias).
template <bool BIAS, bool RELU, bool RES, bool HEAD>
__global__ __launch_bounds__(256)
void gemm_bf16(const ushort_t* __restrict__ A, const ushort_t* __restrict__ Wt,
               const float* __restrict__ bias, ushort_t* __restrict__ Cb,
               float* __restrict__ Cf, int M, int N, int K, int nx) {
  __shared__ ushort_t As[128 * 32];
  __shared__ ushort_t Bs[128 * 32];
  const int tid = threadIdx.x;

  int bid = blockIdx.x;
  {
    const int nwg = gridDim.x;
    const int q = nwg >> 3, r = nwg & 7;
    const int xcd = bid & 7, within = bid >> 3;
    bid = (xcd < r ? xcd * (q + 1) : r * (q + 1) + (xcd - r) * q) + within;
  }
  const int bn = (bid % nx) * 128;
  const int bm = (bid / nx) * 128;

  const int w = tid >> 6, lane = tid & 63;
  const int wr = (w >> 1) * 64, wc = (w & 1) * 64;    // wave tile origin
  const int fr = lane & 15, fq = lane >> 4;           // fragment row, k-quarter

  // staging: lane fetches the k-quarter that belongs at its linear LDS slot
  const int rp = lane >> 2;                           // row-in-16-group
  const int fqs = (lane & 3) ^ ((rp >> 1) & 3);       // k-quarter to fetch
  const ushort_t* Ag0 = A + (size_t)(bm + w * 16 + rp) * K + fqs * 8;
  const ushort_t* Ag1 = Ag0 + (size_t)64 * K;
  const ushort_t* Bg0 = Wt + (size_t)(bn + w * 16 + rp) * K + fqs * 8;
  const ushort_t* Bg1 = Bg0 + (size_t)64 * K;
  ushort_t* Asw0 = As + (w * 16) * 32;                // wave-uniform dests
  ushort_t* Asw1 = As + (64 + w * 16) * 32;
  ushort_t* Bsw0 = Bs + (w * 16) * 32;
  ushort_t* Bsw1 = Bs + (64 + w * 16) * 32;

  // fragment read bases (swizzled slot; rows' bits 1-2 come from fr only)
  const int slotr = (fq ^ ((fr >> 1) & 3)) * 8;
  const ushort_t* Ard = As + (wr + fr) * 32 + slotr;
  const ushort_t* Brd = Bs + (wc + fr) * 32 + slotr;

  f32x4 acc[4][4] = {};

  for (int k0 = 0; k0 < K; k0 += 32) {
    gload_lds16(Ag0 + k0, Asw0);
    gload_lds16(Ag1 + k0, Asw1);
    gload_lds16(Bg0 + k0, Bsw0);
    gload_lds16(Bg1 + k0, Bsw1);
    __syncthreads();                                  // drains vmcnt + barrier
    s16x8 afr[4], bfr[4];
#pragma unroll
    for (int m = 0; m < 4; ++m) afr[m] = *(const s16x8*)(Ard + m * 16 * 32);
#pragma unroll
    for (int n = 0; n < 4; ++n) bfr[n] = *(const s16x8*)(Brd + n * 16 * 32);
#pragma unroll
    for (int m = 0; m < 4; ++m)
#pragma unroll
      for (int n = 0; n < 4; ++n)
        acc[m][n] = __builtin_amdgcn_mfma_f32_16x16x32_bf16(afr[m], bfr[n], acc[m][n], 0, 0, 0);
    __syncthreads();                                  // before next overwrite
  }

  // epilogue: D row = (lane>>4)*4 + j, col = lane&15 (m89/m91-verified layout)
  const int r0 = bm + wr + fq * 4;
  const int c0 = bn + wc + fr;
#pragma unroll
  for (int n = 0; n < 4; ++n) {
    const int col = c0 + n * 16;
    if (HEAD && col >= VV) continue;
    const float bv = BIAS ? bias[col] : 0.f;
#pragma unroll
    for (int m = 0; m < 4; ++m) {
      const int row = r0 + m * 16;
#pragma unroll
      for (int j = 0; j < 4; ++j) {
        float vv = acc[m][n][j] + bv;
        if constexpr (RELU) vv = fmaxf(vv, 0.f);
        if constexpr (HEAD)      Cf[(size_t)(row + j) * VV + col] = vv;
        else if constexpr (RES)  Cf[(size_t)(row + j) * N + col] += vv;
        else                     Cb[(size_t)(row + j) * N + col] = f2b(vv);
      }
    }
  }
}

// ------------- attention: block = (causal-quarter, seq, head); K bf16 in LDS -------------
// qkv: [R][1152] bf16 (q|k|v each [384] = h*64+d). o: [R][384] bf16.
__global__ __launch_bounds__(256)
void attn_kernel(const ushort_t* __restrict__ qkv, ushort_t* __restrict__ o, int cseq) {
  __shared__ ushort_t Ks[256 * 66];          // pad 66: conflict-free uint reads
  __shared__ float att[4][256];              // per-wave row
  const int tid = threadIdx.x;
  const int nb = cseq * HH;
  const int qtr = 3 - blockIdx.x / nb;       // heavy quarters dispatched first
  const int sh = blockIdx.x % nb;
  const int seq = sh / HH, hh = sh % HH;
  const int ng = qtr + 1;                    // k-groups of 64 needed
  const int brow = seq * TT;

  for (int f = tid; f < ng * 2048; f += 256) {
    int s = f >> 5, dp = f & 31;
    *(uint*)&Ks[s * 66 + dp * 2] =
        *(const uint*)&qkv[(size_t)(brow + s) * 1152 + 384 + hh * 64 + dp * 2];
  }
  __syncthreads();

  const int w = tid >> 6, lane = tid & 63;
  const ushort_t* vbase = qkv + (size_t)brow * 1152 + 768 + hh * 64 + lane;

  for (int it = 0; it < 16; ++it) {
    const int t = qtr * 64 + it * 4 + w;     // this wave's query row
    const uint* qrow = (const uint*)(qkv + (size_t)(brow + t) * 1152 + hh * 64);
    u32x4 qv[8];
#pragma unroll
    for (int g = 0; g < 8; ++g) qv[g] = ((const u32x4*)qrow)[g];

    float sc[4] = {0.f, 0.f, 0.f, 0.f};
#pragma unroll
    for (int i = 0; i < 4; ++i) {
      if (i <= qtr) {                        // uniform branch per block
        float s0 = 0.f;
#pragma unroll
        for (int dp = 0; dp < 32; ++dp) {
          uint qp = qv[dp >> 2][dp & 3];
          uint kp = *(const uint*)&Ks[(i * 64 + lane) * 66 + dp * 2];
          s0 += uaf(qp << 16) * uaf(kp << 16) +
                uaf(qp & 0xffff0000u) * uaf(kp & 0xffff0000u);
        }
        sc[i] = s0;
      }
    }

    float m = -INFINITY;
    float sm[4];
#pragma unroll
    for (int i = 0; i < 4; ++i) {
      int s = i * 64 + lane;
      sm[i] = (i <= qtr && s <= t) ? sc[i] * 0.125f : -INFINITY;
      m = fmaxf(m, sm[i]);
    }
#pragma unroll
    for (int off = 32; off; off >>= 1) m = fmaxf(m, __shfl_xor(m, off));
    float p[4], ps = 0.f;
#pragma unroll
    for (int i = 0; i < 4; ++i) {
      p[i] = (sm[i] == -INFINITY) ? 0.f : __expf(sm[i] - m);
      ps += p[i];
    }
#pragma unroll
    for (int off = 32; off; off >>= 1) ps += __shfl_xor(ps, off);
    float inv = 1.f / ps;
#pragma unroll
    for (int i = 0; i < 4; ++i) att[w][i * 64 + lane] = p[i] * inv;
    asm volatile("s_waitcnt lgkmcnt(0)" ::: "memory");   // per-wave LDS write->read

    float outv = 0.f;
    int s = 0;
    for (; s + 8 <= t + 1; s += 8) {
      outv += att[w][s + 0] * b2f(vbase[(size_t)(s + 0) * 1152]) +
              att[w][s + 1] * b2f(vbase[(size_t)(s + 1) * 1152]) +
              att[w][s + 2] * b2f(vbase[(size_t)(s + 2) * 1152]) +
              att[w][s + 3] * b2f(vbase[(size_t)(s + 3) * 1152]) +
              att[w][s + 4] * b2f(vbase[(size_t)(s + 4) * 1152]) +
              att[w][s + 5] * b2f(vbase[(size_t)(s + 5) * 1152]) +
              att[w][s + 6] * b2f(vbase[(size_t)(s + 6) * 1152]) +
              att[w][s + 7] * b2f(vbase[(size_t)(s + 7) * 1152]);
    }
    for (; s <= t; ++s) outv += att[w][s] * b2f(vbase[(size_t)s * 1152]);
    o[(size_t)(brow + t) * 384 + hh * 64 + lane] = f2b(outv);
  }
}

// -------- loss from finished logits: lse + nll, one wave per row --------
__global__ __launch_bounds__(256)
void loss_kernel(const float* __restrict__ logits, const int* __restrict__ targets,
                 float* __restrict__ loss_acc) {
  int wid = threadIdx.x >> 6, lane = threadIdx.x & 63;
  int r = blockIdx.x * 4 + wid;
  const float* lrow = logits + (size_t)r * VV;
  float v = lrow[lane];
  float e64 = lrow[64];
  float m = fmaxf(v, e64);
#pragma unroll
  for (int off = 32; off; off >>= 1) m = fmaxf(m, __shfl_xor(m, off));
  float s = expf(v - m);
#pragma unroll
  for (int off = 32; off; off >>= 1) s += __shfl_xor(s, off);
  s += expf(e64 - m);
  float lse = m + logf(s);
  int t = targets[r];
  float tv = (t < 64) ? __shfl(v, t) : e64;
  if (lane == 0) atomicAdd(loss_acc, (lse - tv) * (1.f / BT));
}

// ---------------- launcher ----------------
extern "C" void kernel_launch(void* const* d_in, const int* in_sizes, int n_in,
                              void* d_out, int out_size, void* d_ws, size_t ws_size,
                              hipStream_t stream) {
  const int* inputs = (const int*)d_in[0];
  const int* targets = (const int*)d_in[1];
  const float* tok_emb = (const float*)d_in[2];
  const float* pos_emb = (const float*)d_in[3];
  const float* Wq = (const float*)d_in[4];
  const float* Wk = (const float*)d_in[5];
  const float* Wv = (const float*)d_in[6];
  const float* Wo = (const float*)d_in[7];
  const float* bo = (const float*)d_in[8];
  const float* ln1_g = (const float*)d_in[9];
  const float* ln1_b = (const float*)d_in[10];
  const float* W1 = (const float*)d_in[11];
  const float* b1 = (const float*)d_in[12];
  const float* W2 = (const float*)d_in[13];
  const float* b2 = (const float*)d_in[14];
  const float* ln2_g = (const float*)d_in[15];
  const float* ln2_b = (const float*)d_in[16];
  const float* lnf_g = (const float*)d_in[17];
  const float* lnf_b = (const float*)d_in[18];
  const float* Wh = (const float*)d_in[19];
  const float* bh = (const float*)d_in[20];

  float* logits = (float*)d_out;
  float* loss = logits + (size_t)BT * VV;

  auto al = [](size_t b) { return (b + 255) & ~(size_t)255; };
  const size_t wq_b = al((size_t)LL * 1152 * 384 * 2);
  const size_t wo_b = al((size_t)LL * 384 * 384 * 2);
  const size_t w1_b = al((size_t)LL * 1536 * 384 * 2);
  const size_t wh_b = al((size_t)128 * 384 * 2);
  const size_t wfix = wq_b + wo_b + 2 * w1_b + wh_b;

  int c = BB;                                  // sequences per chunk
  while (c > 1 && wfix + (size_t)c * 256 * 6144 > ws_size) c >>= 1;
  const int R = c * TT;
  const int nch = BB / c;

  char* p = (char*)d_ws;
  ushort_t* wqkv = (ushort_t*)p; p += wq_b;
  ushort_t* wot  = (ushort_t*)p; p += wo_b;
  ushort_t* w1t  = (ushort_t*)p; p += w1_b;
  ushort_t* w2t  = (ushort_t*)p; p += w1_b;
  ushort_t* whb  = (ushort_t*)p; p += wh_b;
  float* x = (float*)p;          p += (size_t)R * 1536;   // [R,384] f32
  ushort_t* hb = (ushort_t*)p;   p += (size_t)R * 768;    // [R,384] bf16
  ushort_t* ob = (ushort_t*)p;   p += (size_t)R * 768;    // [R,384] bf16
  ushort_t* un = (ushort_t*)p;                            // R*3072 B union
  ushort_t* qkvb = un;                                    // [R,1152] bf16
  ushort_t* midb = un;                                    // [R,1536] bf16

  hipMemsetAsync(loss, 0, 4, stream);
  pack_qkv<<<LL * 1152 * 384 / 256, 256, 0, stream>>>(Wq, Wk, Wv, wqkv);
  pack_wt<<<LL * 384 * 384 / 256, 256, 0, stream>>>(Wo, wot, 384, 384);
  pack_wt<<<LL * 384 * 1536 / 256, 256, 0, stream>>>(W1, w1t, 384, 1536);
  pack_wt<<<LL * 1536 * 384 / 256, 256, 0, stream>>>(W2, w2t, 1536, 384);
  pack_head<<<128 * 384 / 256, 256, 0, stream>>>(Wh, whb);

  const int my = R / 128;
  for (int ch = 0; ch < nch; ++ch) {
    const size_t r0 = (size_t)ch * R;
    embed_kernel<<<R * 96 / 256, 256, 0, stream>>>(inputs + r0, tok_emb, pos_emb, x);
    for (int l = 0; l < LL; ++l) {
      layernorm_384<1><<<R / 4, 256, 0, stream>>>(x, ln1_g + l * EE, ln1_b + l * EE, hb);
      gemm_bf16<false, false, false, false><<<9 * my, 256, 0, stream>>>(
          hb, wqkv + (size_t)l * 1152 * 384, nullptr, qkvb, nullptr, R, 1152, 384, 9);
      attn_kernel<<<c * HH * 4, 256, 0, stream>>>(qkvb, ob, c);
      gemm_bf16<true, false, true, false><<<3 * my, 256, 0, stream>>>(
          ob, wot + (size_t)l * 384 * 384, bo + l * EE, nullptr, x, R, 384, 384, 3);
      layernorm_384<1><<<R / 4, 256, 0, stream>>>(x, ln2_g + l * EE, ln2_b + l * EE, hb);
      gemm_bf16<true, true, false, false><<<12 * my, 256, 0, stream>>>(
          hb, w1t + (size_t)l * 1536 * 384, b1 + l * FF, midb, nullptr, R, 1536, 384, 12);
      gemm_bf16<true, false, true, false><<<3 * my, 256, 0, stream>>>(
          midb, w2t + (size_t)l * 384 * 1536, b2 + l * EE, nullptr, x, R, 384, 1536, 3);
    }
    layernorm_384<1><<<R / 4, 256, 0, stream>>>(x, lnf_g, lnf_b, hb);
    gemm_bf16<true, false, false, true><<<1 * my, 256, 0, stream>>>(
        hb, whb, bh, nullptr, logits + r0 * VV, R, 128, 384, 1);
    loss_kernel<<<R / 4, 256, 0, stream>>>(logits + r0 * VV, targets + r0, loss);
  }
}

// Round 5
// 4391.817 us; speedup vs baseline: 7.4673x; 1.9357x over previous
//
#include <hip/hip_runtime.h>
#include <math.h>

#define LL 6
#define HH 6
#define EE 384
#define FF 1536
#define TT 256
#define BB 256
#define VV 65
constexpr int BT = BB * TT;                 // 65536 rows total

typedef __attribute__((ext_vector_type(8))) short s16x8;   // 8 bf16 (4 VGPR)
typedef __attribute__((ext_vector_type(4))) float f32x4;
typedef __attribute__((ext_vector_type(2))) unsigned int u32x2;
typedef unsigned int uint;
typedef unsigned short ushort_t;

__device__ __forceinline__ float uaf(uint u) { union { uint u; float f; } c; c.u = u; return c.f; }
__device__ __forceinline__ ushort_t f2b(float f) {
  union { float f; uint u; } c; c.f = f;
  uint r = c.u + 0x7fffu + ((c.u >> 16) & 1u);          // RNE
  return (ushort_t)(r >> 16);
}
__device__ __forceinline__ float b2f(ushort_t b) { return uaf((uint)b << 16); }

__device__ __forceinline__ void gload_lds16(const void* g, void* l) {
  __builtin_amdgcn_global_load_lds(
      (const __attribute__((address_space(1))) unsigned int*)g,
      (__attribute__((address_space(3))) unsigned int*)l, 16, 0, 0);
}

// ---------------- embed ----------------
__global__ __launch_bounds__(256)
void embed_kernel(const int* __restrict__ inp, const float* __restrict__ tok,
                  const float* __restrict__ pos, float* __restrict__ x) {
  int idx = blockIdx.x * 256 + threadIdx.x;
  int e4 = idx % (EE / 4);
  int r = idx / (EE / 4);
  int t = r % TT;
  int tk = inp[r];
  float4 a = ((const float4*)tok)[tk * (EE / 4) + e4];
  float4 p = ((const float4*)pos)[t * (EE / 4) + e4];
  float4 o;
  o.x = a.x + p.x; o.y = a.y + p.y; o.z = a.z + p.z; o.w = a.w + p.w;
  ((float4*)x)[idx] = o;
}

// ------- pack QKV weights: [l][h][e][d] f32 -> bf16 [l][n=1152][k=384] -------
__global__ __launch_bounds__(256)
void pack_qkv(const float* __restrict__ Wq, const float* __restrict__ Wk,
              const float* __restrict__ Wv, ushort_t* __restrict__ dst) {
  int idx = blockIdx.x * 256 + threadIdx.x;
  int l = idx / (1152 * 384);
  int r = idx % (1152 * 384);
  int n = r / 384;
  int k = r % 384;
  int which = n / 384;                            // 0:q 1:k 2:v
  int hd = n % 384;
  int h = hd >> 6, d = hd & 63;
  const float* src = which == 0 ? Wq : (which == 1 ? Wk : Wv);
  dst[idx] = f2b(src[((size_t)(l * HH + h) * EE + k) * 64 + d]);
}

// ------- pack generic weight: [l][k][n] f32 -> bf16 [l][n][k] -------
__global__ __launch_bounds__(256)
void pack_wt(const float* __restrict__ src, ushort_t* __restrict__ dst, int Kd, int Nd) {
  int idx = blockIdx.x * 256 + threadIdx.x;
  int l = idx / (Kd * Nd);
  int r = idx % (Kd * Nd);
  int n = r / Kd;
  int k = r % Kd;
  dst[idx] = f2b(src[((size_t)l * Kd + k) * Nd + n]);
}

// ------- pack head: Wh [384][65] f32 -> bf16 [128][384], zero-pad -------
__global__ __launch_bounds__(256)
void pack_head(const float* __restrict__ Wh, ushort_t* __restrict__ dst) {
  int idx = blockIdx.x * 256 + threadIdx.x;
  int n = idx / 384, k = idx % 384;
  dst[idx] = (n < VV) ? f2b(Wh[(size_t)k * VV + n]) : (ushort_t)0;
}

// ---------------- layernorm over E=384, one wave per row ----------------
template <int BF16OUT>
__global__ __launch_bounds__(256)
void layernorm_384(const float* __restrict__ x, const float* __restrict__ g,
                   const float* __restrict__ b, void* __restrict__ outp) {
  int wid = threadIdx.x >> 6, lane = threadIdx.x & 63;
  int row = blockIdx.x * 4 + wid;
  const float* xr = x + (size_t)row * EE;
  float v[6];
  float s = 0.f, s2 = 0.f;
#pragma unroll
  for (int i = 0; i < 6; ++i) {
    v[i] = xr[lane + 64 * i];
    s += v[i];
    s2 += v[i] * v[i];
  }
#pragma unroll
  for (int off = 32; off; off >>= 1) {
    s += __shfl_xor(s, off);
    s2 += __shfl_xor(s2, off);
  }
  float mu = s * (1.f / EE);
  float var = s2 * (1.f / EE) - mu * mu;
  float rs = rsqrtf(var + 1e-5f);
#pragma unroll
  for (int i = 0; i < 6; ++i) {
    int e = lane + 64 * i;
    float val = (v[i] - mu) * rs * g[e] + b[e];
    if constexpr (BF16OUT) ((ushort_t*)outp)[(size_t)row * EE + e] = f2b(val);
    else                    ((float*)outp)[(size_t)row * EE + e] = val;
  }
}

// ------------- bf16 MFMA GEMM, 2-phase double-buffered staging -------------
// A[M,K] bf16, Wt[N,K] bf16 (W^T). M%128==0, N%128==0, K%32==0.
// MODE 0: Cb[M,N] bf16 = (relu)(acc+bias)
// MODE 1: Cf[M,N] f32 += acc+bias (residual)
// MODE 2: head — Cf f32, stride VV, cols<VV
// MODE 3: qkv split — cols<768 -> Cb stride 768; cols>=768 -> Cv[col-768][M] transposed
template <int MODE, bool BIAS, bool RELU>
__global__ __launch_bounds__(256)
void gemm_bf16(const ushort_t* __restrict__ A, const ushort_t* __restrict__ Wt,
               const float* __restrict__ bias, ushort_t* __restrict__ Cb,
               float* __restrict__ Cf, ushort_t* __restrict__ Cv,
               int M, int N, int K, int nx) {
  __shared__ ushort_t As[2 * 128 * 32];
  __shared__ ushort_t Bs[2 * 128 * 32];
  const int tid = threadIdx.x;

  int bid = blockIdx.x;
  {
    const int nwg = gridDim.x;
    const int q = nwg >> 3, rr = nwg & 7;
    const int xcd = bid & 7, within = bid >> 3;
    bid = (xcd < rr ? xcd * (q + 1) : rr * (q + 1) + (xcd - rr) * q) + within;
  }
  const int bn = (bid % nx) * 128;
  const int bm = (bid / nx) * 128;

  const int w = tid >> 6, lane = tid & 63;
  const int wr = (w >> 1) * 64, wc = (w & 1) * 64;
  const int fr = lane & 15, fq = lane >> 4;

  // staging addressing (slot-XOR swizzle, round-3-verified)
  const int rp = lane >> 2;
  const int fqs = (lane & 3) ^ ((rp >> 1) & 3);
  const ushort_t* Ag0 = A + (size_t)(bm + w * 16 + rp) * K + fqs * 8;
  const ushort_t* Ag1 = Ag0 + (size_t)64 * K;
  const ushort_t* Bg0 = Wt + (size_t)(bn + w * 16 + rp) * K + fqs * 8;
  const ushort_t* Bg1 = Bg0 + (size_t)64 * K;

  const int slotr = (fq ^ ((fr >> 1) & 3)) * 8;
  const ushort_t* Ard = As + (wr + fr) * 32 + slotr;
  const ushort_t* Brd = Bs + (wc + fr) * 32 + slotr;

  const int nt = K >> 5;
  auto STAGE = [&](int kt, int b) {
    const int k0 = kt << 5;
    const int bo = b << 12;                       // 4096 elems per buffer
    gload_lds16(Ag0 + k0, As + bo + (w * 16) * 32);
    gload_lds16(Ag1 + k0, As + bo + (64 + w * 16) * 32);
    gload_lds16(Bg0 + k0, Bs + bo + (w * 16) * 32);
    gload_lds16(Bg1 + k0, Bs + bo + (64 + w * 16) * 32);
  };

  f32x4 acc[4][4] = {};
  STAGE(0, 0);
  __syncthreads();

  for (int t = 0; t < nt; ++t) {
    const int bo = (t & 1) << 12;
    if (t + 1 < nt) STAGE(t + 1, (t & 1) ^ 1);    // prefetch flies under MFMA
    s16x8 afr[4], bfr[4];
#pragma unroll
    for (int m = 0; m < 4; ++m) afr[m] = *(const s16x8*)(Ard + bo + m * 512);
#pragma unroll
    for (int n = 0; n < 4; ++n) bfr[n] = *(const s16x8*)(Brd + bo + n * 512);
#pragma unroll
    for (int m = 0; m < 4; ++m)
#pragma unroll
      for (int n = 0; n < 4; ++n)
        acc[m][n] = __builtin_amdgcn_mfma_f32_16x16x32_bf16(afr[m], bfr[n], acc[m][n], 0, 0, 0);
    __syncthreads();                              // drains vmcnt (prefetch) + barrier
  }

  // epilogue: D row = (lane>>4)*4 + j, col = lane&15
  const int r0 = bm + wr + fq * 4;
  const int c0 = bn + wc + fr;
  if constexpr (MODE == 3) {
    if (bn >= 768) {                              // V region: write V^T [384][M]
#pragma unroll
      for (int n = 0; n < 4; ++n) {
        const int col = c0 + n * 16 - 768;
#pragma unroll
        for (int m = 0; m < 4; ++m) {
          const int row = r0 + m * 16;
          uint lo = (uint)f2b(acc[m][n][0]) | ((uint)f2b(acc[m][n][1]) << 16);
          uint hi = (uint)f2b(acc[m][n][2]) | ((uint)f2b(acc[m][n][3]) << 16);
          *(u32x2*)&Cv[(size_t)col * M + row] = u32x2{lo, hi};
        }
      }
    } else {                                      // Q,K region: bf16, stride 768
#pragma unroll
      for (int n = 0; n < 4; ++n) {
        const int col = c0 + n * 16;
#pragma unroll
        for (int m = 0; m < 4; ++m) {
          const int row = r0 + m * 16;
#pragma unroll
          for (int j = 0; j < 4; ++j)
            Cb[(size_t)(row + j) * 768 + col] = f2b(acc[m][n][j]);
        }
      }
    }
    return;
  }
#pragma unroll
  for (int n = 0; n < 4; ++n) {
    const int col = c0 + n * 16;
    if (MODE == 2 && col >= VV) continue;
    const float bv = BIAS ? bias[col] : 0.f;
#pragma unroll
    for (int m = 0; m < 4; ++m) {
      const int row = r0 + m * 16;
#pragma unroll
      for (int j = 0; j < 4; ++j) {
        float vv = acc[m][n][j] + bv;
        if constexpr (RELU) vv = fmaxf(vv, 0.f);
        if constexpr (MODE == 2)      Cf[(size_t)(row + j) * VV + col] = vv;
        else if constexpr (MODE == 1) Cf[(size_t)(row + j) * N + col] += vv;
        else                          Cb[(size_t)(row + j) * N + col] = f2b(vv);
      }
    }
  }
}

// ------------- MFMA attention: one block per (seq, head) -------------
// qk: [R][768] bf16 (q|k, each hh*64+d). vt: [384][R] bf16 (V^T). o: [R][384] bf16.
// 4 waves; wave w handles q-frags q0 = fi*64 + w*16 (fi=0..3, causal-balanced).
// Full score strip in regs (<=16 tiles of 16x16), wave-parallel softmax,
// P -> per-wave LDS (pad 80B rows, conflict-free) -> MFMA A-frags for PV.
__global__ __launch_bounds__(256)
void attn_kernel(const ushort_t* __restrict__ qk, const ushort_t* __restrict__ vt,
                 ushort_t* __restrict__ o, int R) {
  __shared__ ushort_t Ks[256 * 64];          // swizzled: byte = s*128 + (db ^ ((s&7)<<4))
  __shared__ ushort_t Pb[4][16 * 40];        // per-wave P, 80 B rows
  const int tid = threadIdx.x;
  const int w = tid >> 6, lane = tid & 63;
  const int seq = blockIdx.x / HH, hh = blockIdx.x % HH;
  const int brow = seq * TT;

  // stage K: global_load_lds, pre-swizzled source (XOR involution on 16B slots)
  {
    const ushort_t* kbase = qk + (size_t)brow * 768 + 384 + hh * 64;
#pragma unroll
    for (int cc = 0; cc < 8; ++cc) {
      const int ci = cc * 256 + tid;
      const int s = ci >> 3, j = ci & 7;
      const int srcb = (j * 16) ^ ((s & 7) << 4);
      gload_lds16(kbase + (size_t)s * 768 + (srcb >> 1), Ks + cc * 2048 + w * 512);
    }
  }
  __syncthreads();

  const int r = lane & 15, g = lane >> 4;
  ushort_t* pw = &Pb[w][0];

  for (int fi = 0; fi < 4; ++fi) {
    const int q0 = fi * 64 + w * 16;
    const int n_st = (q0 >> 4) + 1;                 // s-tiles needed (diag = last)
    const ushort_t* qrow = qk + (size_t)(brow + q0 + r) * 768 + hh * 64 + g * 8;
    const s16x8 qa0 = *(const s16x8*)qrow;          // d in [g*8, g*8+8) of [0,32)
    const s16x8 qa1 = *(const s16x8*)(qrow + 32);   // d-half 2

    f32x4 S[16];
#pragma unroll
    for (int st = 0; st < 16; ++st) {
      if (st < n_st) {
        const int srow = st * 16 + r;
        const int sw = (srow & 7) << 4;
        const s16x8 kb0 = *(const s16x8*)(Ks + ((srow * 128 + ((g * 16) ^ sw)) >> 1));
        const s16x8 kb1 = *(const s16x8*)(Ks + ((srow * 128 + ((64 + g * 16) ^ sw)) >> 1));
        f32x4 t = {0.f, 0.f, 0.f, 0.f};
        t = __builtin_amdgcn_mfma_f32_16x16x32_bf16(qa0, kb0, t, 0, 0, 0);
        t = __builtin_amdgcn_mfma_f32_16x16x32_bf16(qa1, kb1, t, 0, 0, 0);
        if (st == n_st - 1) {                       // diagonal tile mask
#pragma unroll
          for (int j = 0; j < 4; ++j)
            t[j] = (r <= g * 4 + j) ? t[j] : -1e30f;
        }
        S[st] = t;
      }
    }

    float mrow[4] = {-1e30f, -1e30f, -1e30f, -1e30f};
#pragma unroll
    for (int st = 0; st < 16; ++st)
      if (st < n_st) {
#pragma unroll
        for (int j = 0; j < 4; ++j) mrow[j] = fmaxf(mrow[j], S[st][j]);
      }
#pragma unroll
    for (int j = 0; j < 4; ++j) {
      float m = mrow[j];
      m = fmaxf(m, __shfl_xor(m, 1));
      m = fmaxf(m, __shfl_xor(m, 2));
      m = fmaxf(m, __shfl_xor(m, 4));
      m = fmaxf(m, __shfl_xor(m, 8));
      mrow[j] = m;
    }

    float rsum[4] = {0.f, 0.f, 0.f, 0.f};
    f32x4 O[4] = {f32x4{0,0,0,0}, f32x4{0,0,0,0}, f32x4{0,0,0,0}, f32x4{0,0,0,0}};
    const int n_sc = (n_st + 1) >> 1;
    const ushort_t* vbase = vt + (size_t)(hh * 64 + r) * R + brow + g * 8;
#pragma unroll
    for (int sc = 0; sc < 8; ++sc) {
      if (sc < n_sc) {
        // write P tiles 2sc, 2sc+1 (unnormalized, bf16; zeros for invalid)
#pragma unroll
        for (int tt = 0; tt < 2; ++tt) {
          const int st = sc * 2 + tt;
#pragma unroll
          for (int j = 0; j < 4; ++j) {
            float p = 0.f;
            if (st < n_st) p = __expf((S[st][j] - mrow[j]) * 0.125f);
            rsum[j] += p;
            pw[((g * 4 + j) * 80 + tt * 32 + r * 2) >> 1] = f2b(p);
          }
        }
        asm volatile("s_waitcnt lgkmcnt(0)" ::: "memory");
        __builtin_amdgcn_sched_barrier(0);
        const s16x8 pa = *(const s16x8*)(pw + ((r * 80 + g * 16) >> 1));
#pragma unroll
        for (int dt = 0; dt < 4; ++dt) {
          const s16x8 vb = *(const s16x8*)(vbase + (size_t)dt * 16 * R + sc * 32);
          O[dt] = __builtin_amdgcn_mfma_f32_16x16x32_bf16(pa, vb, O[dt], 0, 0, 0);
        }
      }
    }

#pragma unroll
    for (int j = 0; j < 4; ++j) {
      float s = rsum[j];
      s += __shfl_xor(s, 1);
      s += __shfl_xor(s, 2);
      s += __shfl_xor(s, 4);
      s += __shfl_xor(s, 8);
      rsum[j] = 1.f / s;
    }
    ushort_t* obase = o + (size_t)(brow + q0 + g * 4) * 384 + hh * 64 + r;
#pragma unroll
    for (int j = 0; j < 4; ++j)
#pragma unroll
      for (int dt = 0; dt < 4; ++dt)
        obase[(size_t)j * 384 + dt * 16] = f2b(O[dt][j] * rsum[j]);
  }
}

// -------- loss from finished logits --------
__global__ __launch_bounds__(256)
void loss_kernel(const float* __restrict__ logits, const int* __restrict__ targets,
                 float* __restrict__ loss_acc) {
  int wid = threadIdx.x >> 6, lane = threadIdx.x & 63;
  int r = blockIdx.x * 4 + wid;
  const float* lrow = logits + (size_t)r * VV;
  float v = lrow[lane];
  float e64 = lrow[64];
  float m = fmaxf(v, e64);
#pragma unroll
  for (int off = 32; off; off >>= 1) m = fmaxf(m, __shfl_xor(m, off));
  float s = expf(v - m);
#pragma unroll
  for (int off = 32; off; off >>= 1) s += __shfl_xor(s, off);
  s += expf(e64 - m);
  float lse = m + logf(s);
  int t = targets[r];
  float tv = (t < 64) ? __shfl(v, t) : e64;
  if (lane == 0) atomicAdd(loss_acc, (lse - tv) * (1.f / BT));
}

// ---------------- launcher ----------------
extern "C" void kernel_launch(void* const* d_in, const int* in_sizes, int n_in,
                              void* d_out, int out_size, void* d_ws, size_t ws_size,
                              hipStream_t stream) {
  const int* inputs = (const int*)d_in[0];
  const int* targets = (const int*)d_in[1];
  const float* tok_emb = (const float*)d_in[2];
  const float* pos_emb = (const float*)d_in[3];
  const float* Wq = (const float*)d_in[4];
  const float* Wk = (const float*)d_in[5];
  const float* Wv = (const float*)d_in[6];
  const float* Wo = (const float*)d_in[7];
  const float* bo = (const float*)d_in[8];
  const float* ln1_g = (const float*)d_in[9];
  const float* ln1_b = (const float*)d_in[10];
  const float* W1 = (const float*)d_in[11];
  const float* b1 = (const float*)d_in[12];
  const float* W2 = (const float*)d_in[13];
  const float* b2 = (const float*)d_in[14];
  const float* ln2_g = (const float*)d_in[15];
  const float* ln2_b = (const float*)d_in[16];
  const float* lnf_g = (const float*)d_in[17];
  const float* lnf_b = (const float*)d_in[18];
  const float* Wh = (const float*)d_in[19];
  const float* bh = (const float*)d_in[20];

  float* logits = (float*)d_out;
  float* loss = logits + (size_t)BT * VV;

  auto al = [](size_t b) { return (b + 255) & ~(size_t)255; };
  const size_t wq_b = al((size_t)LL * 1152 * 384 * 2);
  const size_t wo_b = al((size_t)LL * 384 * 384 * 2);
  const size_t w1_b = al((size_t)LL * 1536 * 384 * 2);
  const size_t wh_b = al((size_t)128 * 384 * 2);
  const size_t wfix = wq_b + wo_b + 2 * w1_b + wh_b;

  int c = BB;
  while (c > 1 && wfix + (size_t)c * 256 * 6144 > ws_size) c >>= 1;
  const int R = c * TT;
  const int nch = BB / c;

  char* p = (char*)d_ws;
  ushort_t* wqkv = (ushort_t*)p; p += wq_b;
  ushort_t* wot  = (ushort_t*)p; p += wo_b;
  ushort_t* w1t  = (ushort_t*)p; p += w1_b;
  ushort_t* w2t  = (ushort_t*)p; p += w1_b;
  ushort_t* whb  = (ushort_t*)p; p += wh_b;
  float* x = (float*)p;          p += (size_t)R * 1536;   // [R,384] f32
  ushort_t* hb = (ushort_t*)p;   p += (size_t)R * 768;    // [R,384] bf16
  ushort_t* ob = (ushort_t*)p;   p += (size_t)R * 768;    // [R,384] bf16
  ushort_t* un = (ushort_t*)p;                            // R*3072 B union
  ushort_t* qkb = un;                                     // [R,768] bf16
  ushort_t* vtb = un + (size_t)R * 768;                   // [384,R] bf16
  ushort_t* midb = un;                                    // [R,1536] bf16

  hipMemsetAsync(loss, 0, 4, stream);
  pack_qkv<<<LL * 1152 * 384 / 256, 256, 0, stream>>>(Wq, Wk, Wv, wqkv);
  pack_wt<<<LL * 384 * 384 / 256, 256, 0, stream>>>(Wo, wot, 384, 384);
  pack_wt<<<LL * 384 * 1536 / 256, 256, 0, stream>>>(W1, w1t, 384, 1536);
  pack_wt<<<LL * 1536 * 384 / 256, 256, 0, stream>>>(W2, w2t, 1536, 384);
  pack_head<<<128 * 384 / 256, 256, 0, stream>>>(Wh, whb);

  const int my = R / 128;
  for (int ch = 0; ch < nch; ++ch) {
    const size_t r0 = (size_t)ch * R;
    embed_kernel<<<R * 96 / 256, 256, 0, stream>>>(inputs + r0, tok_emb, pos_emb, x);
    for (int l = 0; l < LL; ++l) {
      layernorm_384<1><<<R / 4, 256, 0, stream>>>(x, ln1_g + l * EE, ln1_b + l * EE, hb);
      gemm_bf16<3, false, false><<<9 * my, 256, 0, stream>>>(
          hb, wqkv + (size_t)l * 1152 * 384, nullptr, qkb, nullptr, vtb, R, 1152, 384, 9);
      attn_kernel<<<c * HH, 256, 0, stream>>>(qkb, vtb, ob, R);
      gemm_bf16<1, true, false><<<3 * my, 256, 0, stream>>>(
          ob, wot + (size_t)l * 384 * 384, bo + l * EE, nullptr, x, nullptr, R, 384, 384, 3);
      layernorm_384<1><<<R / 4, 256, 0, stream>>>(x, ln2_g + l * EE, ln2_b + l * EE, hb);
      gemm_bf16<0, true, true><<<12 * my, 256, 0, stream>>>(
          hb, w1t + (size_t)l * 1536 * 384, b1 + l * FF, midb, nullptr, nullptr, R, 1536, 384, 12);
      gemm_bf16<1, true, false><<<3 * my, 256, 0, stream>>>(
          midb, w2t + (size_t)l * 384 * 1536, b2 + l * EE, nullptr, x, nullptr, R, 384, 1536, 3);
    }
    layernorm_384<1><<<R / 4, 256, 0, stream>>>(x, lnf_g, lnf_b, hb);
    gemm_bf16<2, true, false><<<1 * my, 256, 0, stream>>>(
        hb, whb, bh, nullptr, logits + r0 * VV, nullptr, R, 128, 384, 1);
    loss_kernel<<<R / 4, 256, 0, stream>>>(logits + r0 * VV, targets + r0, loss);
  }
}

// Round 6
// 3578.698 us; speedup vs baseline: 9.1639x; 1.2272x over previous
//
#include <hip/hip_runtime.h>
#include <math.h>

#define LL 6
#define HH 6
#define EE 384
#define FF 1536
#define TT 256
#define BB 256
#define VV 65
constexpr int BT = BB * TT;                 // 65536 rows total

typedef __attribute__((ext_vector_type(8))) short s16x8;   // 8 bf16 (4 VGPR)
typedef __attribute__((ext_vector_type(4))) float f32x4;
typedef __attribute__((ext_vector_type(2))) unsigned int u32x2;
typedef unsigned int uint;
typedef unsigned short ushort_t;

__device__ __forceinline__ float uaf(uint u) { union { uint u; float f; } c; c.u = u; return c.f; }
__device__ __forceinline__ ushort_t f2b(float f) {
  union { float f; uint u; } c; c.f = f;
  uint r = c.u + 0x7fffu + ((c.u >> 16) & 1u);          // RNE
  return (ushort_t)(r >> 16);
}
__device__ __forceinline__ float b2f(ushort_t b) { return uaf((uint)b << 16); }

__device__ __forceinline__ void gload_lds16(const void* g, void* l) {
  __builtin_amdgcn_global_load_lds(
      (const __attribute__((address_space(1))) unsigned int*)g,
      (__attribute__((address_space(3))) unsigned int*)l, 16, 0, 0);
}

// ---------------- embed ----------------
__global__ __launch_bounds__(256)
void embed_kernel(const int* __restrict__ inp, const float* __restrict__ tok,
                  const float* __restrict__ pos, float* __restrict__ x) {
  int idx = blockIdx.x * 256 + threadIdx.x;
  int e4 = idx % (EE / 4);
  int r = idx / (EE / 4);
  int t = r % TT;
  int tk = inp[r];
  float4 a = ((const float4*)tok)[tk * (EE / 4) + e4];
  float4 p = ((const float4*)pos)[t * (EE / 4) + e4];
  float4 o;
  o.x = a.x + p.x; o.y = a.y + p.y; o.z = a.z + p.z; o.w = a.w + p.w;
  ((float4*)x)[idx] = o;
}

// ------- pack QKV weights: [l][h][e][d] f32 -> bf16 [l][n=1152][k=384] -------
__global__ __launch_bounds__(256)
void pack_qkv(const float* __restrict__ Wq, const float* __restrict__ Wk,
              const float* __restrict__ Wv, ushort_t* __restrict__ dst) {
  int idx = blockIdx.x * 256 + threadIdx.x;
  int l = idx / (1152 * 384);
  int r = idx % (1152 * 384);
  int n = r / 384;
  int k = r % 384;
  int which = n / 384;                            // 0:q 1:k 2:v
  int hd = n % 384;
  int h = hd >> 6, d = hd & 63;
  const float* src = which == 0 ? Wq : (which == 1 ? Wk : Wv);
  dst[idx] = f2b(src[((size_t)(l * HH + h) * EE + k) * 64 + d]);
}

// ------- pack generic weight: [l][k][n] f32 -> bf16 [l][n][k] -------
__global__ __launch_bounds__(256)
void pack_wt(const float* __restrict__ src, ushort_t* __restrict__ dst, int Kd, int Nd) {
  int idx = blockIdx.x * 256 + threadIdx.x;
  int l = idx / (Kd * Nd);
  int r = idx % (Kd * Nd);
  int n = r / Kd;
  int k = r % Kd;
  dst[idx] = f2b(src[((size_t)l * Kd + k) * Nd + n]);
}

// ------- pack head: Wh [384][65] f32 -> bf16 [128][384], zero-pad -------
__global__ __launch_bounds__(256)
void pack_head(const float* __restrict__ Wh, ushort_t* __restrict__ dst) {
  int idx = blockIdx.x * 256 + threadIdx.x;
  int n = idx / 384, k = idx % 384;
  dst[idx] = (n < VV) ? f2b(Wh[(size_t)k * VV + n]) : (ushort_t)0;
}

// ---------------- layernorm over E=384, one wave per row ----------------
template <int BF16OUT>
__global__ __launch_bounds__(256)
void layernorm_384(const float* __restrict__ x, const float* __restrict__ g,
                   const float* __restrict__ b, void* __restrict__ outp) {
  int wid = threadIdx.x >> 6, lane = threadIdx.x & 63;
  int row = blockIdx.x * 4 + wid;
  const float* xr = x + (size_t)row * EE;
  float v[6];
  float s = 0.f, s2 = 0.f;
#pragma unroll
  for (int i = 0; i < 6; ++i) {
    v[i] = xr[lane + 64 * i];
    s += v[i];
    s2 += v[i] * v[i];
  }
#pragma unroll
  for (int off = 32; off; off >>= 1) {
    s += __shfl_xor(s, off);
    s2 += __shfl_xor(s2, off);
  }
  float mu = s * (1.f / EE);
  float var = s2 * (1.f / EE) - mu * mu;
  float rs = rsqrtf(var + 1e-5f);
#pragma unroll
  for (int i = 0; i < 6; ++i) {
    int e = lane + 64 * i;
    float val = (v[i] - mu) * rs * g[e] + b[e];
    if constexpr (BF16OUT) ((ushort_t*)outp)[(size_t)row * EE + e] = f2b(val);
    else                    ((float*)outp)[(size_t)row * EE + e] = val;
  }
}

// ------------- bf16 MFMA GEMM, double-buffered, counted-vmcnt pipeline -------------
// A[M,K] bf16, Wt[N,K] bf16 (W^T). M%128==0, N%128==0, K%32==0.
// MODE 0: Cb[M,N] bf16 = (relu)(acc+bias)
// MODE 1: Cf[M,N] f32 += acc+bias (residual)
// MODE 2: head — Cf f32, stride VV, cols<VV
// MODE 3: qkv split — cols<768 -> Cb stride 768; cols>=768 -> Cv[col-768][M] transposed
template <int MODE, bool BIAS, bool RELU>
__global__ __launch_bounds__(256)
void gemm_bf16(const ushort_t* __restrict__ A, const ushort_t* __restrict__ Wt,
               const float* __restrict__ bias, ushort_t* __restrict__ Cb,
               float* __restrict__ Cf, ushort_t* __restrict__ Cv,
               int M, int N, int K, int nx) {
  __shared__ ushort_t As[2 * 128 * 32];
  __shared__ ushort_t Bs[2 * 128 * 32];
  const int tid = threadIdx.x;

  int bid = blockIdx.x;
  {
    const int nwg = gridDim.x;
    const int q = nwg >> 3, rr = nwg & 7;
    const int xcd = bid & 7, within = bid >> 3;
    bid = (xcd < rr ? xcd * (q + 1) : rr * (q + 1) + (xcd - rr) * q) + within;
  }
  const int bn = (bid % nx) * 128;
  const int bm = (bid / nx) * 128;

  const int w = tid >> 6, lane = tid & 63;
  const int wr = (w >> 1) * 64, wc = (w & 1) * 64;
  const int fr = lane & 15, fq = lane >> 4;

  // staging addressing (slot-XOR swizzle, round-3-verified)
  const int rp = lane >> 2;
  const int fqs = (lane & 3) ^ ((rp >> 1) & 3);
  const ushort_t* Ag0 = A + (size_t)(bm + w * 16 + rp) * K + fqs * 8;
  const ushort_t* Ag1 = Ag0 + (size_t)64 * K;
  const ushort_t* Bg0 = Wt + (size_t)(bn + w * 16 + rp) * K + fqs * 8;
  const ushort_t* Bg1 = Bg0 + (size_t)64 * K;

  const int slotr = (fq ^ ((fr >> 1) & 3)) * 8;
  const ushort_t* Ard = As + (wr + fr) * 32 + slotr;
  const ushort_t* Brd = Bs + (wc + fr) * 32 + slotr;

  const int nt = K >> 5;
  auto STAGE = [&](int kt, int b) {
    const int k0 = kt << 5;
    const int bo = b << 12;                       // 4096 elems per buffer
    gload_lds16(Ag0 + k0, As + bo + (w * 16) * 32);
    gload_lds16(Ag1 + k0, As + bo + (64 + w * 16) * 32);
    gload_lds16(Bg0 + k0, Bs + bo + (w * 16) * 32);
    gload_lds16(Bg1 + k0, Bs + bo + (64 + w * 16) * 32);
  };

  f32x4 acc[4][4] = {};
  STAGE(0, 0);

  for (int t = 0; t < nt; ++t) {
    const int bo = (t & 1) << 12;
    if (t + 1 < nt) {
      STAGE(t + 1, (t & 1) ^ 1);                  // next tile's 4 loads in flight
      asm volatile("s_waitcnt vmcnt(4)" ::: "memory");   // wait buf t only
    } else {
      asm volatile("s_waitcnt vmcnt(0)" ::: "memory");
    }
    __builtin_amdgcn_s_barrier();                 // all waves: buf t written
    __builtin_amdgcn_sched_barrier(0);
    s16x8 afr[4], bfr[4];
#pragma unroll
    for (int m = 0; m < 4; ++m) afr[m] = *(const s16x8*)(Ard + bo + m * 512);
#pragma unroll
    for (int n = 0; n < 4; ++n) bfr[n] = *(const s16x8*)(Brd + bo + n * 512);
#pragma unroll
    for (int m = 0; m < 4; ++m)
#pragma unroll
      for (int n = 0; n < 4; ++n)
        acc[m][n] = __builtin_amdgcn_mfma_f32_16x16x32_bf16(afr[m], bfr[n], acc[m][n], 0, 0, 0);
    __builtin_amdgcn_sched_barrier(0);
    __builtin_amdgcn_s_barrier();                 // reads done before buf overwrite
  }

  // epilogue: D row = (lane>>4)*4 + j, col = lane&15
  const int r0 = bm + wr + fq * 4;
  const int c0 = bn + wc + fr;
  if constexpr (MODE == 3) {
    if (bn >= 768) {                              // V region: write V^T [384][M]
#pragma unroll
      for (int n = 0; n < 4; ++n) {
        const int col = c0 + n * 16 - 768;
#pragma unroll
        for (int m = 0; m < 4; ++m) {
          const int row = r0 + m * 16;
          uint lo = (uint)f2b(acc[m][n][0]) | ((uint)f2b(acc[m][n][1]) << 16);
          uint hi = (uint)f2b(acc[m][n][2]) | ((uint)f2b(acc[m][n][3]) << 16);
          *(u32x2*)&Cv[(size_t)col * M + row] = u32x2{lo, hi};
        }
      }
    } else {                                      // Q,K region: bf16, stride 768
#pragma unroll
      for (int n = 0; n < 4; ++n) {
        const int col = c0 + n * 16;
#pragma unroll
        for (int m = 0; m < 4; ++m) {
          const int row = r0 + m * 16;
#pragma unroll
          for (int j = 0; j < 4; ++j)
            Cb[(size_t)(row + j) * 768 + col] = f2b(acc[m][n][j]);
        }
      }
    }
    return;
  }
#pragma unroll
  for (int n = 0; n < 4; ++n) {
    const int col = c0 + n * 16;
    if (MODE == 2 && col >= VV) continue;
    const float bv = BIAS ? bias[col] : 0.f;
#pragma unroll
    for (int m = 0; m < 4; ++m) {
      const int row = r0 + m * 16;
#pragma unroll
      for (int j = 0; j < 4; ++j) {
        float vv = acc[m][n][j] + bv;
        if constexpr (RELU) vv = fmaxf(vv, 0.f);
        if constexpr (MODE == 2)      Cf[(size_t)(row + j) * VV + col] = vv;
        else if constexpr (MODE == 1) Cf[(size_t)(row + j) * N + col] += vv;
        else                          Cb[(size_t)(row + j) * N + col] = f2b(vv);
      }
    }
  }
}

// ------------- MFMA attention: one block per (seq, head) -------------
// qk: [R][768] bf16 (q|k, each hh*64+d). vt: [384][R] bf16 (V^T). o: [R][384] bf16.
__global__ __launch_bounds__(256)
void attn_kernel(const ushort_t* __restrict__ qk, const ushort_t* __restrict__ vt,
                 ushort_t* __restrict__ o, int R) {
  __shared__ ushort_t Ks[256 * 64];          // swizzled: byte = s*128 + (db ^ ((s&7)<<4))
  __shared__ ushort_t Pb[4][16 * 40];        // per-wave P, 80 B rows
  const int tid = threadIdx.x;
  const int w = tid >> 6, lane = tid & 63;
  const int seq = blockIdx.x / HH, hh = blockIdx.x % HH;
  const int brow = seq * TT;

  // stage K: global_load_lds, pre-swizzled source (XOR involution on 16B slots)
  {
    const ushort_t* kbase = qk + (size_t)brow * 768 + 384 + hh * 64;
#pragma unroll
    for (int cc = 0; cc < 8; ++cc) {
      const int ci = cc * 256 + tid;
      const int s = ci >> 3, j = ci & 7;
      const int srcb = (j * 16) ^ ((s & 7) << 4);
      gload_lds16(kbase + (size_t)s * 768 + (srcb >> 1), Ks + cc * 2048 + w * 512);
    }
  }
  __syncthreads();

  const int r = lane & 15, g = lane >> 4;
  ushort_t* pw = &Pb[w][0];

  for (int fi = 0; fi < 4; ++fi) {
    const int q0 = fi * 64 + w * 16;
    const int n_st = (q0 >> 4) + 1;                 // s-tiles needed (diag = last)
    const ushort_t* qrow = qk + (size_t)(brow + q0 + r) * 768 + hh * 64 + g * 8;
    const s16x8 qa0 = *(const s16x8*)qrow;          // d in [g*8, g*8+8) of [0,32)
    const s16x8 qa1 = *(const s16x8*)(qrow + 32);   // d-half 2

    f32x4 S[16];
#pragma unroll
    for (int st = 0; st < 16; ++st) {
      if (st < n_st) {
        const int srow = st * 16 + r;
        const int sw = (srow & 7) << 4;
        const s16x8 kb0 = *(const s16x8*)(Ks + ((srow * 128 + ((g * 16) ^ sw)) >> 1));
        const s16x8 kb1 = *(const s16x8*)(Ks + ((srow * 128 + ((64 + g * 16) ^ sw)) >> 1));
        f32x4 t = {0.f, 0.f, 0.f, 0.f};
        t = __builtin_amdgcn_mfma_f32_16x16x32_bf16(qa0, kb0, t, 0, 0, 0);
        t = __builtin_amdgcn_mfma_f32_16x16x32_bf16(qa1, kb1, t, 0, 0, 0);
        if (st == n_st - 1) {                       // diagonal tile mask
#pragma unroll
          for (int j = 0; j < 4; ++j)
            t[j] = (r <= g * 4 + j) ? t[j] : -1e30f;
        }
        S[st] = t;
      }
    }

    float mrow[4] = {-1e30f, -1e30f, -1e30f, -1e30f};
#pragma unroll
    for (int st = 0; st < 16; ++st)
      if (st < n_st) {
#pragma unroll
        for (int j = 0; j < 4; ++j) mrow[j] = fmaxf(mrow[j], S[st][j]);
      }
#pragma unroll
    for (int j = 0; j < 4; ++j) {
      float m = mrow[j];
      m = fmaxf(m, __shfl_xor(m, 1));
      m = fmaxf(m, __shfl_xor(m, 2));
      m = fmaxf(m, __shfl_xor(m, 4));
      m = fmaxf(m, __shfl_xor(m, 8));
      mrow[j] = m;
    }

    float rsum[4] = {0.f, 0.f, 0.f, 0.f};
    f32x4 O[4] = {f32x4{0,0,0,0}, f32x4{0,0,0,0}, f32x4{0,0,0,0}, f32x4{0,0,0,0}};
    const int n_sc = (n_st + 1) >> 1;
    const ushort_t* vbase = vt + (size_t)(hh * 64 + r) * R + brow + g * 8;
#pragma unroll
    for (int sc = 0; sc < 8; ++sc) {
      if (sc < n_sc) {
#pragma unroll
        for (int tt = 0; tt < 2; ++tt) {
          const int st = sc * 2 + tt;
#pragma unroll
          for (int j = 0; j < 4; ++j) {
            float p = 0.f;
            if (st < n_st) p = __expf((S[st][j] - mrow[j]) * 0.125f);
            rsum[j] += p;
            pw[((g * 4 + j) * 80 + tt * 32 + r * 2) >> 1] = f2b(p);
          }
        }
        asm volatile("s_waitcnt lgkmcnt(0)" ::: "memory");
        __builtin_amdgcn_sched_barrier(0);
        const s16x8 pa = *(const s16x8*)(pw + ((r * 80 + g * 16) >> 1));
#pragma unroll
        for (int dt = 0; dt < 4; ++dt) {
          const s16x8 vb = *(const s16x8*)(vbase + (size_t)dt * 16 * R + sc * 32);
          O[dt] = __builtin_amdgcn_mfma_f32_16x16x32_bf16(pa, vb, O[dt], 0, 0, 0);
        }
      }
    }

#pragma unroll
    for (int j = 0; j < 4; ++j) {
      float s = rsum[j];
      s += __shfl_xor(s, 1);
      s += __shfl_xor(s, 2);
      s += __shfl_xor(s, 4);
      s += __shfl_xor(s, 8);
      rsum[j] = 1.f / s;
    }
    ushort_t* obase = o + (size_t)(brow + q0 + g * 4) * 384 + hh * 64 + r;
#pragma unroll
    for (int j = 0; j < 4; ++j)
#pragma unroll
      for (int dt = 0; dt < 4; ++dt)
        obase[(size_t)j * 384 + dt * 16] = f2b(O[dt][j] * rsum[j]);
  }
}

// -------- loss: grid-stride rows, block-reduce, one atomic per block --------
__global__ __launch_bounds__(256)
void loss_kernel(const float* __restrict__ logits, const int* __restrict__ targets,
                 float* __restrict__ loss_acc, int R) {
  __shared__ float red[4];
  int wid = threadIdx.x >> 6, lane = threadIdx.x & 63;
  float lsum = 0.f;
  for (int r = blockIdx.x * 4 + wid; r < R; r += gridDim.x * 4) {
    const float* lrow = logits + (size_t)r * VV;
    float v = lrow[lane];
    float e64 = lrow[64];
    float m = fmaxf(v, e64);
#pragma unroll
    for (int off = 32; off; off >>= 1) m = fmaxf(m, __shfl_xor(m, off));
    float s = expf(v - m);
#pragma unroll
    for (int off = 32; off; off >>= 1) s += __shfl_xor(s, off);
    s += expf(e64 - m);
    float lse = m + logf(s);
    int t = targets[r];
    float tv = (t < 64) ? __shfl(v, t) : e64;
    lsum += lse - tv;
  }
  if (lane == 0) red[wid] = lsum;
  __syncthreads();
  if (threadIdx.x == 0)
    atomicAdd(loss_acc, (red[0] + red[1] + red[2] + red[3]) * (1.f / BT));
}

// ---------------- launcher ----------------
extern "C" void kernel_launch(void* const* d_in, const int* in_sizes, int n_in,
                              void* d_out, int out_size, void* d_ws, size_t ws_size,
                              hipStream_t stream) {
  const int* inputs = (const int*)d_in[0];
  const int* targets = (const int*)d_in[1];
  const float* tok_emb = (const float*)d_in[2];
  const float* pos_emb = (const float*)d_in[3];
  const float* Wq = (const float*)d_in[4];
  const float* Wk = (const float*)d_in[5];
  const float* Wv = (const float*)d_in[6];
  const float* Wo = (const float*)d_in[7];
  const float* bo = (const float*)d_in[8];
  const float* ln1_g = (const float*)d_in[9];
  const float* ln1_b = (const float*)d_in[10];
  const float* W1 = (const float*)d_in[11];
  const float* b1 = (const float*)d_in[12];
  const float* W2 = (const float*)d_in[13];
  const float* b2 = (const float*)d_in[14];
  const float* ln2_g = (const float*)d_in[15];
  const float* ln2_b = (const float*)d_in[16];
  const float* lnf_g = (const float*)d_in[17];
  const float* lnf_b = (const float*)d_in[18];
  const float* Wh = (const float*)d_in[19];
  const float* bh = (const float*)d_in[20];

  float* logits = (float*)d_out;
  float* loss = logits + (size_t)BT * VV;

  auto al = [](size_t b) { return (b + 255) & ~(size_t)255; };
  const size_t wq_b = al((size_t)LL * 1152 * 384 * 2);
  const size_t wo_b = al((size_t)LL * 384 * 384 * 2);
  const size_t w1_b = al((size_t)LL * 1536 * 384 * 2);
  const size_t wh_b = al((size_t)128 * 384 * 2);
  const size_t wfix = wq_b + wo_b + 2 * w1_b + wh_b;

  int c = BB;
  while (c > 1 && wfix + (size_t)c * 256 * 6144 > ws_size) c >>= 1;
  const int R = c * TT;
  const int nch = BB / c;

  char* p = (char*)d_ws;
  ushort_t* wqkv = (ushort_t*)p; p += wq_b;
  ushort_t* wot  = (ushort_t*)p; p += wo_b;
  ushort_t* w1t  = (ushort_t*)p; p += w1_b;
  ushort_t* w2t  = (ushort_t*)p; p += w1_b;
  ushort_t* whb  = (ushort_t*)p; p += wh_b;
  float* x = (float*)p;          p += (size_t)R * 1536;   // [R,384] f32
  ushort_t* hb = (ushort_t*)p;   p += (size_t)R * 768;    // [R,384] bf16
  ushort_t* ob = (ushort_t*)p;   p += (size_t)R * 768;    // [R,384] bf16
  ushort_t* un = (ushort_t*)p;                            // R*3072 B union
  ushort_t* qkb = un;                                     // [R,768] bf16
  ushort_t* vtb = un + (size_t)R * 768;                   // [384,R] bf16
  ushort_t* midb = un;                                    // [R,1536] bf16

  hipMemsetAsync(loss, 0, 4, stream);
  pack_qkv<<<LL * 1152 * 384 / 256, 256, 0, stream>>>(Wq, Wk, Wv, wqkv);
  pack_wt<<<LL * 384 * 384 / 256, 256, 0, stream>>>(Wo, wot, 384, 384);
  pack_wt<<<LL * 384 * 1536 / 256, 256, 0, stream>>>(W1, w1t, 384, 1536);
  pack_wt<<<LL * 1536 * 384 / 256, 256, 0, stream>>>(W2, w2t, 1536, 384);
  pack_head<<<128 * 384 / 256, 256, 0, stream>>>(Wh, whb);

  const int my = R / 128;
  for (int ch = 0; ch < nch; ++ch) {
    const size_t r0 = (size_t)ch * R;
    embed_kernel<<<R * 96 / 256, 256, 0, stream>>>(inputs + r0, tok_emb, pos_emb, x);
    for (int l = 0; l < LL; ++l) {
      layernorm_384<1><<<R / 4, 256, 0, stream>>>(x, ln1_g + l * EE, ln1_b + l * EE, hb);
      gemm_bf16<3, false, false><<<9 * my, 256, 0, stream>>>(
          hb, wqkv + (size_t)l * 1152 * 384, nullptr, qkb, nullptr, vtb, R, 1152, 384, 9);
      attn_kernel<<<c * HH, 256, 0, stream>>>(qkb, vtb, ob, R);
      gemm_bf16<1, true, false><<<3 * my, 256, 0, stream>>>(
          ob, wot + (size_t)l * 384 * 384, bo + l * EE, nullptr, x, nullptr, R, 384, 384, 3);
      layernorm_384<1><<<R / 4, 256, 0, stream>>>(x, ln2_g + l * EE, ln2_b + l * EE, hb);
      gemm_bf16<0, true, true><<<12 * my, 256, 0, stream>>>(
          hb, w1t + (size_t)l * 1536 * 384, b1 + l * FF, midb, nullptr, nullptr, R, 1536, 384, 12);
      gemm_bf16<1, true, false><<<3 * my, 256, 0, stream>>>(
          midb, w2t + (size_t)l * 384 * 1536, b2 + l * EE, nullptr, x, nullptr, R, 384, 1536, 3);
    }
    layernorm_384<1><<<R / 4, 256, 0, stream>>>(x, lnf_g, lnf_b, hb);
    gemm_bf16<2, true, false><<<1 * my, 256, 0, stream>>>(
        hb, whb, bh, nullptr, logits + r0 * VV, nullptr, R, 128, 384, 1);
    loss_kernel<<<1024, 256, 0, stream>>>(logits + r0 * VV, targets + r0, loss, R);
  }
}